// Round 4
// baseline (599.380 us; speedup 1.0000x reference)
//
#include <hip/hip_runtime.h>

typedef unsigned short u16;
typedef unsigned int u32;

typedef __bf16 bf16x8 __attribute__((ext_vector_type(8)));
typedef float f32x4 __attribute__((ext_vector_type(4)));

#define EPI_BF16 0
#define EPI_ELU1 1
#define EPI_RELU 2
#define EPI_ADDRES_F32 3

__device__ __forceinline__ float bf2f(u16 x) {
    u32 u = ((u32)x) << 16;
    return __uint_as_float(u);
}
__device__ __forceinline__ u16 f2bf(float f) {
    u32 u = __float_as_uint(f);
    u32 r = (u + 0x7FFFu + ((u >> 16) & 1u)) >> 16;
    return (u16)r;
}

// async global->LDS, 16B per lane; LDS dest = wave-uniform base + lane*16
__device__ __forceinline__ void gload_lds16(const u16* g, u16* l) {
    __builtin_amdgcn_global_load_lds(
        (const __attribute__((address_space(1))) u32*)g,
        (__attribute__((address_space(3))) u32*)l, 16, 0, 0);
}

// ---------------------------------------------------------------------------
// fp32 -> bf16 conversion (vectorized, 4 elems/thread)
// ---------------------------------------------------------------------------
__global__ __launch_bounds__(256) void f2b_k(const float* __restrict__ in,
                                             u16* __restrict__ out, int n) {
    int i = (blockIdx.x * 256 + threadIdx.x) * 4;
    if (i >= n) return;
    float4 f = *(const float4*)(in + i);
    ushort4 o;
    o.x = f2bf(f.x); o.y = f2bf(f.y); o.z = f2bf(f.z); o.w = f2bf(f.w);
    *(ushort4*)(out + i) = o;
}

// ---------------------------------------------------------------------------
// Weight transpose + cast: in fp32 [R][C] -> out bf16 [C][R]
// ---------------------------------------------------------------------------
__global__ void transpose_k(const float* __restrict__ in, u16* __restrict__ out,
                            int R, int C) {
    int idx = blockIdx.x * 256 + threadIdx.x;
    if (idx >= R * C) return;
    int c = idx / R, r = idx % R;        // out index = c*R + r
    out[idx] = f2bf(in[(long)r * C + c]);
}

// ---------------------------------------------------------------------------
// GEMM: C[M,N] = A[M,K] (bf16) @ Bt[N,K]^T (bf16), fp32 accum, fused epilogue.
// 128x128 tile, BK=32, 4 waves (2x2 of 64x64), mfma_f32_16x16x32_bf16.
//
// Round-4 pipeline (T3+T4): quad-buffered LDS, prefetch distance 3, COUNTED
// vmcnt (steady vmcnt(8): 12 loads in flight, only oldest tile must land) +
// raw s_barrier (NO __syncthreads -> no vmcnt(0) drain; that drain was the
// round-3 stall: MfmaUtil 17%, VALU 12%, HBM 16% all idle). sched_barrier(0)
// pins the prefetch-issue AFTER the barrier (buffer-rotation safety: buf
// (kt+3)&3 was read in step kt-1; issue only once all waves passed step-kt
// barrier).
//
// LDS layout per buffer: [4 k-groups][128 rows][16B] (same bytes, different
// indexing). DMA writes stay linear (wave-uniform base + lane*16); fragment
// ds_read_b128 now hits 16 consecutive 16B slots per lane-group -> 2
// lanes/bank = conflict-free (old row-major stride-64B layout was 8-way,
// SQ_LDS_BANK_CONFLICT 4.19M). Bit-identical data -> bit-identical results.
//
// XCD-chunked swizzle kept (round-3: FETCH 150->57.5MB on FFN-GEMM2).
// ---------------------------------------------------------------------------
__global__ __launch_bounds__(256) void gemm_bt(
    const u16* __restrict__ A, const u16* __restrict__ Bt,
    void* __restrict__ C, const float* __restrict__ Res,
    int M, int N, int K, int epi)
{
    __shared__ __align__(16) u16 As[4][4096];   // 4 buffers x 8KB
    __shared__ __align__(16) u16 Bs[4][4096];

    int t = threadIdx.x;

    // XCD-chunked swizzle (bijective; all gemm grids are %8==0)
    int gx = gridDim.x;
    int nwg = gx * gridDim.y;
    int bid = blockIdx.y * gx + blockIdx.x;
    if ((nwg & 7) == 0) {
        int cpx = nwg >> 3;
        bid = (bid & 7) * cpx + (bid >> 3);
    }
    int m0 = (bid / gx) * 128, n0 = (bid % gx) * 128;

    int wave = t >> 6, lane = t & 63;
    int wm = (wave >> 1) * 64, wn = (wave & 1) * 64;
    int lrow = lane & 15;
    int lg = lane >> 4;                  // k-group 0..3 (8 k-elems each)

    f32x4 acc[4][4] = {};

    // staging: lane stages row srow for k-groups (wave>>1) and (wave>>1)+2.
    // dest slot (16B units): call1 = wave*64+lane -> [g=wave>>1][row], 
    // call2 = 256+wave*64+lane -> [g=(wave>>1)+2][row]; row=(wave&1)*64+lane.
    int srow = (wave & 1) * 64 + lane;
    int sg8 = (wave >> 1) * 8;
    const u16* pA0 = A + (long)(m0 + srow) * K + sg8;
    const u16* pB0 = Bt + (long)(n0 + srow) * K + sg8;

    int nt = K >> 5;

    // prologue: stage tiles 0..2 (12 loads/wave in flight)
    for (int pt = 0; pt < 3 && pt < nt; ++pt) {
        int k0 = pt << 5;
        u16* a = As[pt] + wave * 512;
        u16* b = Bs[pt] + wave * 512;
        gload_lds16(pA0 + k0, a);
        gload_lds16(pA0 + k0 + 16, a + 2048);
        gload_lds16(pB0 + k0, b);
        gload_lds16(pB0 + k0 + 16, b + 2048);
    }

    for (int kt = 0; kt < nt; ++kt) {
        // counted wait: only tile kt's 4 loads must have landed
        int rem = nt - 1 - kt;
        if (rem >= 2)      asm volatile("s_waitcnt vmcnt(8)" ::: "memory");
        else if (rem == 1) asm volatile("s_waitcnt vmcnt(4)" ::: "memory");
        else               asm volatile("s_waitcnt vmcnt(0)" ::: "memory");
        __builtin_amdgcn_s_barrier();
        __builtin_amdgcn_sched_barrier(0);   // pin prefetch-issue after barrier

        if (kt + 3 < nt) {
            int k0 = (kt + 3) << 5;
            u16* a = As[(kt + 3) & 3] + wave * 512;
            u16* b = Bs[(kt + 3) & 3] + wave * 512;
            gload_lds16(pA0 + k0, a);
            gload_lds16(pA0 + k0 + 16, a + 2048);
            gload_lds16(pB0 + k0, b);
            gload_lds16(pB0 + k0 + 16, b + 2048);
        }

        const u16* As_c = As[kt & 3] + lg * 1024;
        const u16* Bs_c = Bs[kt & 3] + lg * 1024;
        bf16x8 af[4], bfr[4];
#pragma unroll
        for (int mi = 0; mi < 4; mi++)
            af[mi] = *(const bf16x8*)(As_c + (wm + mi * 16 + lrow) * 8);
#pragma unroll
        for (int ni = 0; ni < 4; ni++)
            bfr[ni] = *(const bf16x8*)(Bs_c + (wn + ni * 16 + lrow) * 8);
#pragma unroll
        for (int mi = 0; mi < 4; mi++)
#pragma unroll
            for (int ni = 0; ni < 4; ni++)
                acc[mi][ni] = __builtin_amdgcn_mfma_f32_16x16x32_bf16(
                    af[mi], bfr[ni], acc[mi][ni], 0, 0, 0);
    }

    // Epilogue: D[row=(lane>>4)*4+r][col=lane&15] per 16x16 tile (verified m89/m91)
    int rq = (lane >> 4) * 4;
    int colb = n0 + wn + (lane & 15);
#pragma unroll
    for (int mi = 0; mi < 4; mi++) {
#pragma unroll
        for (int ni = 0; ni < 4; ni++) {
#pragma unroll
            for (int r = 0; r < 4; r++) {
                int row = m0 + wm + mi * 16 + rq + r;
                int col = colb + ni * 16;
                long idx = (long)row * N + col;
                float v0 = acc[mi][ni][r];
                if (epi == EPI_ELU1) {
                    float v = v0 > 0.f ? v0 + 1.f : __expf(v0);
                    ((u16*)C)[idx] = f2bf(v);
                } else if (epi == EPI_RELU) {
                    ((u16*)C)[idx] = f2bf(v0 > 0.f ? v0 : 0.f);
                } else if (epi == EPI_ADDRES_F32) {
                    ((float*)C)[idx] = v0 + Res[idx];
                } else {
                    ((u16*)C)[idx] = f2bf(v0);
                }
            }
        }
    }
}

// ---------------------------------------------------------------------------
// KV stage 1: per (bh, 64-s split) partial KVp[d][v] = sum_s K[s,d]*V[s,v]
// and KsPart[d] = sum_s K[s,d]. grid (32, 64), 256 threads.
// ---------------------------------------------------------------------------
__global__ __launch_bounds__(256) void kv_part(
    const u16* __restrict__ Kf, const u16* __restrict__ Vf,
    float* __restrict__ Part, float* __restrict__ KsPart)
{
    __shared__ float sKf[64 * 68];   // stride 68: conflict-light, 16B aligned
    __shared__ float sVf[64 * 68];
    int bh = blockIdx.x;
    int b = bh >> 3, h = bh & 7;
    int s0 = blockIdx.y * 64;
    int t = threadIdx.x;
    int d = t & 63, vg = t >> 6;

    {   // stage FULL 64x64 K and V tiles, bf16 -> fp32 (256 thr x 16 elems)
        int row = t >> 2, c16 = (t & 3) * 16;
        long g = ((long)b * 4096 + s0 + row) * 512 + h * 64 + c16;
        uint4 kk0 = *(const uint4*)(Kf + g);
        uint4 kk1 = *(const uint4*)(Kf + g + 8);
        uint4 vv0 = *(const uint4*)(Vf + g);
        uint4 vv1 = *(const uint4*)(Vf + g + 8);
        float* dk = sKf + row * 68 + c16;
        float* dv = sVf + row * 68 + c16;
        u32 kw[8] = {kk0.x, kk0.y, kk0.z, kk0.w, kk1.x, kk1.y, kk1.z, kk1.w};
        u32 vw[8] = {vv0.x, vv0.y, vv0.z, vv0.w, vv1.x, vv1.y, vv1.z, vv1.w};
#pragma unroll
        for (int j = 0; j < 8; j++) {
            dk[2 * j]     = __uint_as_float(kw[j] << 16);
            dk[2 * j + 1] = __uint_as_float(kw[j] & 0xFFFF0000u);
            dv[2 * j]     = __uint_as_float(vw[j] << 16);
            dv[2 * j + 1] = __uint_as_float(vw[j] & 0xFFFF0000u);
        }
    }
    __syncthreads();

    float acc[16] = {};
    float ks = 0.f;
#pragma unroll 4
    for (int s = 0; s < 64; s++) {
        float kd = sKf[s * 68 + d];
        if (vg == 0) ks += kd;                    // wave-uniform branch
        const float* vr = sVf + s * 68 + vg * 16; // wave-uniform -> broadcast
        float4 v0 = *(const float4*)(vr);
        float4 v1 = *(const float4*)(vr + 4);
        float4 v2 = *(const float4*)(vr + 8);
        float4 v3 = *(const float4*)(vr + 12);
        acc[0]  += kd * v0.x; acc[1]  += kd * v0.y;
        acc[2]  += kd * v0.z; acc[3]  += kd * v0.w;
        acc[4]  += kd * v1.x; acc[5]  += kd * v1.y;
        acc[6]  += kd * v1.z; acc[7]  += kd * v1.w;
        acc[8]  += kd * v2.x; acc[9]  += kd * v2.y;
        acc[10] += kd * v2.z; acc[11] += kd * v2.w;
        acc[12] += kd * v3.x; acc[13] += kd * v3.y;
        acc[14] += kd * v3.z; acc[15] += kd * v3.w;
    }
    float* pp = Part + ((long)bh * 64 + blockIdx.y) * 4096 + d * 64 + vg * 16;
#pragma unroll
    for (int j = 0; j < 16; j++) pp[j] = acc[j];
    if (vg == 0) KsPart[((bh * 64) + blockIdx.y) * 64 + d] = ks;
}

// ---------------------------------------------------------------------------
// KV stage 2: KV[bh][dv] = sum over 64 splits; Ksum folded into tail blocks.
// grid 520 x 256: idx<131072 -> KV, else -> Ksum (2048 entries).
// ---------------------------------------------------------------------------
__global__ __launch_bounds__(256) void kv_reduce(
    const float* __restrict__ Part, const float* __restrict__ KsPart,
    float* __restrict__ KV, float* __restrict__ Ksum)
{
    int i = blockIdx.x * 256 + threadIdx.x;
    if (i < 131072) {
        int bh = i >> 12, dv = i & 4095;
        const float* p = Part + (long)bh * 64 * 4096 + dv;
        float s = 0.f;
#pragma unroll 8
        for (int sp = 0; sp < 64; sp++) s += p[(long)sp * 4096];
        KV[i] = s;
    } else if (i < 133120) {
        int j = i - 131072;
        int bh = j >> 6, d = j & 63;
        const float* p = KsPart + bh * 64 * 64 + d;
        float s = 0.f;
#pragma unroll 8
        for (int sp = 0; sp < 64; sp++) s += p[sp * 64];
        Ksum[j] = s;
    }
}

// ---------------------------------------------------------------------------
// msg[b,l,h,v] = (sum_d Q[b,l,h,d]*KV[bh][d][v]) / (Q . Ksum + eps)
// lane = v; KV column in 64 VGPRs (from LDS-transposed copy); Q rows read as
// wave-uniform ds_read_b128 broadcasts; Z precomputed per row. All fp32.
// ---------------------------------------------------------------------------
__global__ __launch_bounds__(256) void msg_k(
    const u16* __restrict__ Q, const float* __restrict__ KV,
    const float* __restrict__ Ksum, u16* __restrict__ Msg)
{
    __shared__ float sKVt[64 * 68];  // [v][d], pad 68 (stride%32==4 -> 2-way max)
    __shared__ float sQ[64 * 68];    // [l_local][d] fp32
    __shared__ float sKs[64];
    __shared__ float sZ[64];

    int bh = blockIdx.x;
    int b = bh >> 3, h = bh & 7;
    int l0 = blockIdx.y * 64;
    int t = threadIdx.x, wave = t >> 6, lane = t & 63;

    {   // stage KV[bh] (fp32 [d][v]) -> sKVt[v][d] (transposed). 16 elems/thr.
        const float* src = KV + (long)bh * 4096 + t * 16;
        int d = t >> 2;              // source row (d index)
        int v0 = (t & 3) * 16;       // source col base (v index)
        float4 a0 = *(const float4*)(src);
        float4 a1 = *(const float4*)(src + 4);
        float4 a2 = *(const float4*)(src + 8);
        float4 a3 = *(const float4*)(src + 12);
        float tmp[16] = {a0.x, a0.y, a0.z, a0.w, a1.x, a1.y, a1.z, a1.w,
                         a2.x, a2.y, a2.z, a2.w, a3.x, a3.y, a3.z, a3.w};
#pragma unroll
        for (int j = 0; j < 16; j++) sKVt[(v0 + j) * 68 + d] = tmp[j];
    }
    {   // stage Q tile rows l0..l0+63 (bf16 -> fp32). 16 elems/thr.
        int row = t >> 2, c = (t & 3) * 16;
        const u16* src = Q + ((long)b * 4096 + l0 + row) * 512 + h * 64 + c;
        uint4 q0 = *(const uint4*)(src);
        uint4 q1 = *(const uint4*)(src + 8);
        float* dq = sQ + row * 68 + c;
        u32 qw[8] = {q0.x, q0.y, q0.z, q0.w, q1.x, q1.y, q1.z, q1.w};
#pragma unroll
        for (int j = 0; j < 8; j++) {
            dq[2 * j]     = __uint_as_float(qw[j] << 16);
            dq[2 * j + 1] = __uint_as_float(qw[j] & 0xFFFF0000u);
        }
    }
    if (t < 64) sKs[t] = Ksum[bh * 64 + t];
    __syncthreads();

    // hoist this lane's KV column into registers (one-time, 16x ds_read_b128)
    float kv[64];
    {
        const float* kr = sKVt + lane * 68;
#pragma unroll
        for (int j = 0; j < 16; j++) {
            float4 x = *(const float4*)(kr + 4 * j);
            kv[4 * j]     = x.x; kv[4 * j + 1] = x.y;
            kv[4 * j + 2] = x.z; kv[4 * j + 3] = x.w;
        }
    }
    // per-row normalizer (wave 0 only; sKs reads are uniform -> broadcast)
    if (t < 64) {
        const float* qr = sQ + t * 68;
        float zp = 0.f;
#pragma unroll
        for (int d = 0; d < 64; d++) zp += qr[d] * sKs[d];
        sZ[t] = 1.f / (zp + 1e-6f);
    }
    __syncthreads();

    const long obase = ((long)b * 4096 + l0) * 512 + h * 64 + lane;
    int lbase = wave * 16;
#pragma unroll 4
    for (int i = 0; i < 16; i++) {
        int ll = lbase + i;
        const float* qr = sQ + ll * 68;
        float a0 = 0.f, a1 = 0.f, a2 = 0.f, a3 = 0.f;  // 4 indep chains
#pragma unroll
        for (int db = 0; db < 16; db++) {
            float4 q4 = *(const float4*)(qr + 4 * db);  // wave-uniform bcast
            a0 += q4.x * kv[4 * db];
            a1 += q4.y * kv[4 * db + 1];
            a2 += q4.z * kv[4 * db + 2];
            a3 += q4.w * kv[4 * db + 3];
        }
        float acc = (a0 + a1) + (a2 + a3);
        Msg[obase + (long)ll * 512] = f2bf(acc * sZ[ll]);
    }
}

// ---------------------------------------------------------------------------
// LayerNorm over 512 cols, fp32 input, fp32 gamma/beta.
// out_f32 != 0 -> write fp32 to OutF, else bf16 to OutB.
// ---------------------------------------------------------------------------
__global__ __launch_bounds__(256) void ln_k(
    const float* __restrict__ X, const float* __restrict__ g,
    const float* __restrict__ bta, u16* __restrict__ OutB,
    float* __restrict__ OutF, int out_f32)
{
    int row = blockIdx.x;
    const float* x = X + (long)row * 512;
    int t = threadIdx.x;
    float x0 = x[t], x1 = x[t + 256];
    float s = x0 + x1, sq = x0 * x0 + x1 * x1;
#pragma unroll
    for (int off = 32; off > 0; off >>= 1) {
        s += __shfl_xor(s, off, 64);
        sq += __shfl_xor(sq, off, 64);
    }
    __shared__ float rs[4], rq[4];
    int wave = t >> 6, lane = t & 63;
    if (lane == 0) { rs[wave] = s; rq[wave] = sq; }
    __syncthreads();
    s = rs[0] + rs[1] + rs[2] + rs[3];
    sq = rq[0] + rq[1] + rq[2] + rq[3];
    float mu = s * (1.f / 512.f);
    float var = sq * (1.f / 512.f) - mu * mu;
    float rstd = rsqrtf(var + 1e-5f);
    float y0 = (x0 - mu) * rstd * g[t] + bta[t];
    float y1 = (x1 - mu) * rstd * g[t + 256] + bta[t + 256];
    if (out_f32) {
        OutF[(long)row * 512 + t] = y0;
        OutF[(long)row * 512 + t + 256] = y1;
    } else {
        OutB[(long)row * 512 + t] = f2bf(y0);
        OutB[(long)row * 512 + t + 256] = f2bf(y1);
    }
}

// ---------------------------------------------------------------------------
extern "C" void kernel_launch(void* const* d_in, const int* in_sizes, int n_in,
                              void* d_out, int out_size, void* d_ws, size_t ws_size,
                              hipStream_t stream) {
    const float* q  = (const float*)d_in[0];
    const float* k  = (const float*)d_in[1];
    const float* v  = (const float*)d_in[2];
    const float* Wq = (const float*)d_in[3];
    const float* Wk = (const float*)d_in[4];
    const float* Wv = (const float*)d_in[5];
    const float* Wm = (const float*)d_in[6];
    const float* W1 = (const float*)d_in[7];
    const float* W2 = (const float*)d_in[8];
    const float* g1 = (const float*)d_in[9];
    const float* b1 = (const float*)d_in[10];
    const float* g2 = (const float*)d_in[11];
    const float* b2 = (const float*)d_in[12];

    char* ws = (char*)d_ws;
    // workspace layout (bytes); high-water ~124MB
    u16* WTq = (u16*)(ws + 0);            // 512KB each
    u16* WTk = (u16*)(ws + 524288);
    u16* WTv = (u16*)(ws + 1048576);
    u16* WTm = (u16*)(ws + 1572864);
    u16* W1T = (u16*)(ws + 2097152);      // [2048,512] 2MB
    u16* W2T = (u16*)(ws + 4194304);      // [512,2048] 2MB
    u16* qc  = (u16*)(ws + 6291456);      // bf16 casts of q/k/v, 16.8MB each
    u16* kc  = (u16*)(ws + 23068672);
    u16* vc  = (u16*)(ws + 39845888);
    u16* Qb  = (u16*)(ws + 56623104);     // elu+1 projections
    u16* Kb  = (u16*)(ws + 73400320);
    u16* Vb  = (u16*)(ws + 90177536);
    float* KVb = (float*)(ws + 106954752); // 512KB
    float* KSb = (float*)(ws + 107479040); // 8KB
    u16* Msg = (u16*)(ws + 107487232);    // 16.8MB -> high-water 124264448
    float* Part = (float*)(ws + 23068672); // 33.5MB partial KV (kc/vc dead)
    float* KsPart = (float*)(ws + 6291456);// 512KB (qc dead after projections)
    float* xpre = (float*)(ws + 23068672); // 33.5MB (Part dead after reduce)
    u16* x1  = qc;                         // reuses qc (KsPart dead by LN1)
    u16* Hid = (u16*)(ws + 56623104);     // 67MB, reuses Qb..Msg (dead at FFN)

    // fp32 -> bf16 casts of activations
    f2b_k<<<dim3(8192), 256, 0, stream>>>(q, qc, 8388608);
    f2b_k<<<dim3(8192), 256, 0, stream>>>(k, kc, 8388608);
    f2b_k<<<dim3(8192), 256, 0, stream>>>(v, vc, 8388608);

    // weight transposes + cast ([in,out] fp32 -> [out,in] bf16)
    transpose_k<<<dim3(1024), 256, 0, stream>>>(Wq, WTq, 512, 512);
    transpose_k<<<dim3(1024), 256, 0, stream>>>(Wk, WTk, 512, 512);
    transpose_k<<<dim3(1024), 256, 0, stream>>>(Wv, WTv, 512, 512);
    transpose_k<<<dim3(1024), 256, 0, stream>>>(Wm, WTm, 512, 512);
    transpose_k<<<dim3(4096), 256, 0, stream>>>(W1, W1T, 512, 2048);
    transpose_k<<<dim3(4096), 256, 0, stream>>>(W2, W2T, 2048, 512);

    // projections with fused activation
    gemm_bt<<<dim3(4, 128), 256, 0, stream>>>(qc, WTq, Qb, nullptr, 16384, 512, 512, EPI_ELU1);
    gemm_bt<<<dim3(4, 128), 256, 0, stream>>>(kc, WTk, Kb, nullptr, 16384, 512, 512, EPI_ELU1);
    gemm_bt<<<dim3(4, 128), 256, 0, stream>>>(vc, WTv, Vb, nullptr, 16384, 512, 512, EPI_BF16);

    // linear attention: two-stage KV (no atomics), then msg
    kv_part<<<dim3(32, 64), 256, 0, stream>>>(Kb, Vb, Part, KsPart);
    kv_reduce<<<dim3(520), 256, 0, stream>>>(Part, KsPart, KVb, KSb);
    msg_k<<<dim3(32, 64), 256, 0, stream>>>(Qb, KVb, KSb, Msg);

    // merge + residual(q fp32) + LN1 (bf16 out for FFN input)
    gemm_bt<<<dim3(4, 128), 256, 0, stream>>>(Msg, WTm, xpre, q, 16384, 512, 512, EPI_ADDRES_F32);
    ln_k<<<dim3(16384), 256, 0, stream>>>(xpre, g1, b1, x1, nullptr, 0);

    // FFN + residual(q fp32) + LN2 (fp32 out -> d_out)
    gemm_bt<<<dim3(16, 128), 256, 0, stream>>>(x1, W1T, Hid, nullptr, 16384, 2048, 512, EPI_RELU);
    gemm_bt<<<dim3(4, 128), 256, 0, stream>>>(Hid, W2T, xpre, q, 16384, 512, 2048, EPI_ADDRES_F32);
    ln_k<<<dim3(16384), 256, 0, stream>>>(xpre, g2, b2, nullptr, (float*)d_out, 1);
}

// Round 6
// 583.237 us; speedup vs baseline: 1.0277x; 1.0277x over previous
//
#include <hip/hip_runtime.h>

typedef unsigned short u16;
typedef unsigned int u32;

typedef __bf16 bf16x8 __attribute__((ext_vector_type(8)));
typedef float f32x4 __attribute__((ext_vector_type(4)));

#define EPI_BF16 0
#define EPI_ELU1 1
#define EPI_RELU 2
#define EPI_ADDRES_F32 3

__device__ __forceinline__ float bf2f(u16 x) {
    u32 u = ((u32)x) << 16;
    return __uint_as_float(u);
}
__device__ __forceinline__ u16 f2bf(float f) {
    u32 u = __float_as_uint(f);
    u32 r = (u + 0x7FFFu + ((u >> 16) & 1u)) >> 16;
    return (u16)r;
}

// async global->LDS, 16B per lane; LDS dest = wave-uniform base + lane*16
__device__ __forceinline__ void gload_lds16(const u16* g, u16* l) {
    __builtin_amdgcn_global_load_lds(
        (const __attribute__((address_space(1))) u32*)g,
        (__attribute__((address_space(3))) u32*)l, 16, 0, 0);
}

// ---------------------------------------------------------------------------
// fp32 -> bf16 conversion (vectorized, 4 elems/thread)
// ---------------------------------------------------------------------------
__global__ __launch_bounds__(256) void f2b_k(const float* __restrict__ in,
                                             u16* __restrict__ out, int n) {
    int i = (blockIdx.x * 256 + threadIdx.x) * 4;
    if (i >= n) return;
    float4 f = *(const float4*)(in + i);
    ushort4 o;
    o.x = f2bf(f.x); o.y = f2bf(f.y); o.z = f2bf(f.z); o.w = f2bf(f.w);
    *(ushort4*)(out + i) = o;
}

// ---------------------------------------------------------------------------
// Weight transpose + cast: in fp32 [R][C] -> out bf16 [C][R]
// ---------------------------------------------------------------------------
__global__ void transpose_k(const float* __restrict__ in, u16* __restrict__ out,
                            int R, int C) {
    int idx = blockIdx.x * 256 + threadIdx.x;
    if (idx >= R * C) return;
    int c = idx / R, r = idx % R;        // out index = c*R + r
    out[idx] = f2bf(in[(long)r * C + c]);
}

// ---------------------------------------------------------------------------
// GEMM: C[M,N] = A[M,K] (bf16) @ Bt[N,K]^T (bf16), fp32 accum, fused epilogue.
// 128x128 tile, BK=32, 4 waves (2x2 of 64x64), mfma_f32_16x16x32_bf16.
//
// Depth-3 pipeline, 48KB LDS (r4 post-mortem: 4-deep's 64KB LDS cut FFN1
// from 4 to 2 blocks/CU -> 101us regression; r3's 2-deep drain covered only
// ~400cyc, not the ~900cyc HBM tail seen via FETCH=57MB). Depth-3 gives
// prefetch distance 2 (~800cyc, covers HBM) at 3 blocks/CU.
//   per step: wait vmcnt(4) [tile kt landed, kt+1 STAYS IN FLIGHT across the
//   barrier]; raw s_barrier (no vmcnt(0) drain); sched_barrier(0) pins the
//   T(kt+2) issue after the barrier (buf (kt+2)%3 last read at step kt-1);
//   ds_read+MFMA on buf kt%3. Tail: vmcnt(0) at kt=nt-1.
// Wait-BEFORE-barrier: each wave certifies its own tile-kt loads, barrier
// certifies all waves' (r4-verified ordering; r4 passed correctness).
//
// LDS layout per buffer: [4 k-groups][128 rows][16B] -> DMA stays linear,
// fragment ds_read_b128 is conflict-free (r4: SQ_LDS_BANK_CONFLICT 4.19M->0).
// XCD-chunked swizzle kept (r3: FETCH 150->57.5MB on FFN-GEMM2).
// ---------------------------------------------------------------------------
__global__ __launch_bounds__(256) void gemm_bt(
    const u16* __restrict__ A, const u16* __restrict__ Bt,
    void* __restrict__ C, const float* __restrict__ Res,
    int M, int N, int K, int epi)
{
    __shared__ __align__(16) u16 As[3][4096];   // 3 buffers x 8KB
    __shared__ __align__(16) u16 Bs[3][4096];

    int t = threadIdx.x;

    // XCD-chunked swizzle (bijective; all gemm grids are %8==0)
    int gx = gridDim.x;
    int nwg = gx * gridDim.y;
    int bid = blockIdx.y * gx + blockIdx.x;
    if ((nwg & 7) == 0) {
        int cpx = nwg >> 3;
        bid = (bid & 7) * cpx + (bid >> 3);
    }
    int m0 = (bid / gx) * 128, n0 = (bid % gx) * 128;

    int wave = t >> 6, lane = t & 63;
    int wm = (wave >> 1) * 64, wn = (wave & 1) * 64;
    int lrow = lane & 15;
    int lg = lane >> 4;                  // k-group 0..3 (8 k-elems each)

    f32x4 acc[4][4] = {};

    // staging (r4-verified mapping): lane stages row srow for k-groups
    // (wave>>1) and (wave>>1)+2; dest slots wave*64+lane and +256 (16B units).
    int srow = (wave & 1) * 64 + lane;
    int sg8 = (wave >> 1) * 8;
    const u16* pA0 = A + (long)(m0 + srow) * K + sg8;
    const u16* pB0 = Bt + (long)(n0 + srow) * K + sg8;

    int nt = K >> 5;

    // prologue: stage tiles 0,1 into buffers 0,1 (8 loads/wave in flight)
    for (int pt = 0; pt < 2 && pt < nt; ++pt) {
        int k0 = pt << 5;
        u16* a = As[pt] + wave * 512;
        u16* b = Bs[pt] + wave * 512;
        gload_lds16(pA0 + k0, a);
        gload_lds16(pA0 + k0 + 16, a + 2048);
        gload_lds16(pB0 + k0, b);
        gload_lds16(pB0 + k0 + 16, b + 2048);
    }

    int cur = 0;
    for (int kt = 0; kt < nt; ++kt) {
        // counted wait: tile kt's 4 loads landed; tile kt+1 stays in flight
        if (kt < nt - 1) asm volatile("s_waitcnt vmcnt(4)" ::: "memory");
        else             asm volatile("s_waitcnt vmcnt(0)" ::: "memory");
        __builtin_amdgcn_s_barrier();
        __builtin_amdgcn_sched_barrier(0);   // pin prefetch-issue after barrier

        if (kt + 2 < nt) {
            int k0 = (kt + 2) << 5;
            int nb = cur + 2; if (nb >= 3) nb -= 3;
            u16* a = As[nb] + wave * 512;
            u16* b = Bs[nb] + wave * 512;
            gload_lds16(pA0 + k0, a);
            gload_lds16(pA0 + k0 + 16, a + 2048);
            gload_lds16(pB0 + k0, b);
            gload_lds16(pB0 + k0 + 16, b + 2048);
        }

        const u16* As_c = As[cur] + lg * 1024;
        const u16* Bs_c = Bs[cur] + lg * 1024;
        bf16x8 af[4], bfr[4];
#pragma unroll
        for (int mi = 0; mi < 4; mi++)
            af[mi] = *(const bf16x8*)(As_c + (wm + mi * 16 + lrow) * 8);
#pragma unroll
        for (int ni = 0; ni < 4; ni++)
            bfr[ni] = *(const bf16x8*)(Bs_c + (wn + ni * 16 + lrow) * 8);
#pragma unroll
        for (int mi = 0; mi < 4; mi++)
#pragma unroll
            for (int ni = 0; ni < 4; ni++)
                acc[mi][ni] = __builtin_amdgcn_mfma_f32_16x16x32_bf16(
                    af[mi], bfr[ni], acc[mi][ni], 0, 0, 0);

        cur = (cur == 2) ? 0 : cur + 1;
    }

    // Epilogue: D[row=(lane>>4)*4+r][col=lane&15] per 16x16 tile (verified m89/m91)
    int rq = (lane >> 4) * 4;
    int colb = n0 + wn + (lane & 15);
#pragma unroll
    for (int mi = 0; mi < 4; mi++) {
#pragma unroll
        for (int ni = 0; ni < 4; ni++) {
#pragma unroll
            for (int r = 0; r < 4; r++) {
                int row = m0 + wm + mi * 16 + rq + r;
                int col = colb + ni * 16;
                long idx = (long)row * N + col;
                float v0 = acc[mi][ni][r];
                if (epi == EPI_ELU1) {
                    float v = v0 > 0.f ? v0 + 1.f : __expf(v0);
                    ((u16*)C)[idx] = f2bf(v);
                } else if (epi == EPI_RELU) {
                    ((u16*)C)[idx] = f2bf(v0 > 0.f ? v0 : 0.f);
                } else if (epi == EPI_ADDRES_F32) {
                    ((float*)C)[idx] = v0 + Res[idx];
                } else {
                    ((u16*)C)[idx] = f2bf(v0);
                }
            }
        }
    }
}

// ---------------------------------------------------------------------------
// KV stage 1: per (bh, 64-s split) partial KVp[d][v] = sum_s K[s,d]*V[s,v]
// and KsPart[d] = sum_s K[s,d]. grid (32, 64), 256 threads.
// ---------------------------------------------------------------------------
__global__ __launch_bounds__(256) void kv_part(
    const u16* __restrict__ Kf, const u16* __restrict__ Vf,
    float* __restrict__ Part, float* __restrict__ KsPart)
{
    __shared__ float sKf[64 * 68];   // stride 68: conflict-light, 16B aligned
    __shared__ float sVf[64 * 68];
    int bh = blockIdx.x;
    int b = bh >> 3, h = bh & 7;
    int s0 = blockIdx.y * 64;
    int t = threadIdx.x;
    int d = t & 63, vg = t >> 6;

    {   // stage FULL 64x64 K and V tiles, bf16 -> fp32 (256 thr x 16 elems)
        int row = t >> 2, c16 = (t & 3) * 16;
        long g = ((long)b * 4096 + s0 + row) * 512 + h * 64 + c16;
        uint4 kk0 = *(const uint4*)(Kf + g);
        uint4 kk1 = *(const uint4*)(Kf + g + 8);
        uint4 vv0 = *(const uint4*)(Vf + g);
        uint4 vv1 = *(const uint4*)(Vf + g + 8);
        float* dk = sKf + row * 68 + c16;
        float* dv = sVf + row * 68 + c16;
        u32 kw[8] = {kk0.x, kk0.y, kk0.z, kk0.w, kk1.x, kk1.y, kk1.z, kk1.w};
        u32 vw[8] = {vv0.x, vv0.y, vv0.z, vv0.w, vv1.x, vv1.y, vv1.z, vv1.w};
#pragma unroll
        for (int j = 0; j < 8; j++) {
            dk[2 * j]     = __uint_as_float(kw[j] << 16);
            dk[2 * j + 1] = __uint_as_float(kw[j] & 0xFFFF0000u);
            dv[2 * j]     = __uint_as_float(vw[j] << 16);
            dv[2 * j + 1] = __uint_as_float(vw[j] & 0xFFFF0000u);
        }
    }
    __syncthreads();

    float acc[16] = {};
    float ks = 0.f;
#pragma unroll 4
    for (int s = 0; s < 64; s++) {
        float kd = sKf[s * 68 + d];
        if (vg == 0) ks += kd;                    // wave-uniform branch
        const float* vr = sVf + s * 68 + vg * 16; // wave-uniform -> broadcast
        float4 v0 = *(const float4*)(vr);
        float4 v1 = *(const float4*)(vr + 4);
        float4 v2 = *(const float4*)(vr + 8);
        float4 v3 = *(const float4*)(vr + 12);
        acc[0]  += kd * v0.x; acc[1]  += kd * v0.y;
        acc[2]  += kd * v0.z; acc[3]  += kd * v0.w;
        acc[4]  += kd * v1.x; acc[5]  += kd * v1.y;
        acc[6]  += kd * v1.z; acc[7]  += kd * v1.w;
        acc[8]  += kd * v2.x; acc[9]  += kd * v2.y;
        acc[10] += kd * v2.z; acc[11] += kd * v2.w;
        acc[12] += kd * v3.x; acc[13] += kd * v3.y;
        acc[14] += kd * v3.z; acc[15] += kd * v3.w;
    }
    float* pp = Part + ((long)bh * 64 + blockIdx.y) * 4096 + d * 64 + vg * 16;
#pragma unroll
    for (int j = 0; j < 16; j++) pp[j] = acc[j];
    if (vg == 0) KsPart[((bh * 64) + blockIdx.y) * 64 + d] = ks;
}

// ---------------------------------------------------------------------------
// KV stage 2: KV[bh][dv] = sum over 64 splits; Ksum folded into tail blocks.
// grid 520 x 256: idx<131072 -> KV, else -> Ksum (2048 entries).
// ---------------------------------------------------------------------------
__global__ __launch_bounds__(256) void kv_reduce(
    const float* __restrict__ Part, const float* __restrict__ KsPart,
    float* __restrict__ KV, float* __restrict__ Ksum)
{
    int i = blockIdx.x * 256 + threadIdx.x;
    if (i < 131072) {
        int bh = i >> 12, dv = i & 4095;
        const float* p = Part + (long)bh * 64 * 4096 + dv;
        float s = 0.f;
#pragma unroll 8
        for (int sp = 0; sp < 64; sp++) s += p[(long)sp * 4096];
        KV[i] = s;
    } else if (i < 133120) {
        int j = i - 131072;
        int bh = j >> 6, d = j & 63;
        const float* p = KsPart + bh * 64 * 64 + d;
        float s = 0.f;
#pragma unroll 8
        for (int sp = 0; sp < 64; sp++) s += p[sp * 64];
        Ksum[j] = s;
    }
}

// ---------------------------------------------------------------------------
// msg[b,l,h,v] = (sum_d Q[b,l,h,d]*KV[bh][d][v]) / (Q . Ksum + eps)
// lane = v; KV column in 64 VGPRs (from LDS-transposed copy); Q rows read as
// wave-uniform ds_read_b128 broadcasts; Z precomputed per row. All fp32.
// ---------------------------------------------------------------------------
__global__ __launch_bounds__(256) void msg_k(
    const u16* __restrict__ Q, const float* __restrict__ KV,
    const float* __restrict__ Ksum, u16* __restrict__ Msg)
{
    __shared__ float sKVt[64 * 68];  // [v][d], pad 68 (stride%32==4 -> 2-way max)
    __shared__ float sQ[64 * 68];    // [l_local][d] fp32
    __shared__ float sKs[64];
    __shared__ float sZ[64];

    int bh = blockIdx.x;
    int b = bh >> 3, h = bh & 7;
    int l0 = blockIdx.y * 64;
    int t = threadIdx.x, wave = t >> 6, lane = t & 63;

    {   // stage KV[bh] (fp32 [d][v]) -> sKVt[v][d] (transposed). 16 elems/thr.
        const float* src = KV + (long)bh * 4096 + t * 16;
        int d = t >> 2;              // source row (d index)
        int v0 = (t & 3) * 16;       // source col base (v index)
        float4 a0 = *(const float4*)(src);
        float4 a1 = *(const float4*)(src + 4);
        float4 a2 = *(const float4*)(src + 8);
        float4 a3 = *(const float4*)(src + 12);
        float tmp[16] = {a0.x, a0.y, a0.z, a0.w, a1.x, a1.y, a1.z, a1.w,
                         a2.x, a2.y, a2.z, a2.w, a3.x, a3.y, a3.z, a3.w};
#pragma unroll
        for (int j = 0; j < 16; j++) sKVt[(v0 + j) * 68 + d] = tmp[j];
    }
    {   // stage Q tile rows l0..l0+63 (bf16 -> fp32). 16 elems/thr.
        int row = t >> 2, c = (t & 3) * 16;
        const u16* src = Q + ((long)b * 4096 + l0 + row) * 512 + h * 64 + c;
        uint4 q0 = *(const uint4*)(src);
        uint4 q1 = *(const uint4*)(src + 8);
        float* dq = sQ + row * 68 + c;
        u32 qw[8] = {q0.x, q0.y, q0.z, q0.w, q1.x, q1.y, q1.z, q1.w};
#pragma unroll
        for (int j = 0; j < 8; j++) {
            dq[2 * j]     = __uint_as_float(qw[j] << 16);
            dq[2 * j + 1] = __uint_as_float(qw[j] & 0xFFFF0000u);
        }
    }
    if (t < 64) sKs[t] = Ksum[bh * 64 + t];
    __syncthreads();

    // hoist this lane's KV column into registers (one-time, 16x ds_read_b128)
    float kv[64];
    {
        const float* kr = sKVt + lane * 68;
#pragma unroll
        for (int j = 0; j < 16; j++) {
            float4 x = *(const float4*)(kr + 4 * j);
            kv[4 * j]     = x.x; kv[4 * j + 1] = x.y;
            kv[4 * j + 2] = x.z; kv[4 * j + 3] = x.w;
        }
    }
    // per-row normalizer (wave 0 only; sKs reads are uniform -> broadcast)
    if (t < 64) {
        const float* qr = sQ + t * 68;
        float zp = 0.f;
#pragma unroll
        for (int d = 0; d < 64; d++) zp += qr[d] * sKs[d];
        sZ[t] = 1.f / (zp + 1e-6f);
    }
    __syncthreads();

    const long obase = ((long)b * 4096 + l0) * 512 + h * 64 + lane;
    int lbase = wave * 16;
#pragma unroll 4
    for (int i = 0; i < 16; i++) {
        int ll = lbase + i;
        const float* qr = sQ + ll * 68;
        float a0 = 0.f, a1 = 0.f, a2 = 0.f, a3 = 0.f;  // 4 indep chains
#pragma unroll
        for (int db = 0; db < 16; db++) {
            float4 q4 = *(const float4*)(qr + 4 * db);  // wave-uniform bcast
            a0 += q4.x * kv[4 * db];
            a1 += q4.y * kv[4 * db + 1];
            a2 += q4.z * kv[4 * db + 2];
            a3 += q4.w * kv[4 * db + 3];
        }
        float acc = (a0 + a1) + (a2 + a3);
        Msg[obase + (long)ll * 512] = f2bf(acc * sZ[ll]);
    }
}

// ---------------------------------------------------------------------------
// LayerNorm over 512 cols, fp32 input, fp32 gamma/beta.
// out_f32 != 0 -> write fp32 to OutF, else bf16 to OutB.
// ---------------------------------------------------------------------------
__global__ __launch_bounds__(256) void ln_k(
    const float* __restrict__ X, const float* __restrict__ g,
    const float* __restrict__ bta, u16* __restrict__ OutB,
    float* __restrict__ OutF, int out_f32)
{
    int row = blockIdx.x;
    const float* x = X + (long)row * 512;
    int t = threadIdx.x;
    float x0 = x[t], x1 = x[t + 256];
    float s = x0 + x1, sq = x0 * x0 + x1 * x1;
#pragma unroll
    for (int off = 32; off > 0; off >>= 1) {
        s += __shfl_xor(s, off, 64);
        sq += __shfl_xor(sq, off, 64);
    }
    __shared__ float rs[4], rq[4];
    int wave = t >> 6, lane = t & 63;
    if (lane == 0) { rs[wave] = s; rq[wave] = sq; }
    __syncthreads();
    s = rs[0] + rs[1] + rs[2] + rs[3];
    sq = rq[0] + rq[1] + rq[2] + rq[3];
    float mu = s * (1.f / 512.f);
    float var = sq * (1.f / 512.f) - mu * mu;
    float rstd = rsqrtf(var + 1e-5f);
    float y0 = (x0 - mu) * rstd * g[t] + bta[t];
    float y1 = (x1 - mu) * rstd * g[t + 256] + bta[t + 256];
    if (out_f32) {
        OutF[(long)row * 512 + t] = y0;
        OutF[(long)row * 512 + t + 256] = y1;
    } else {
        OutB[(long)row * 512 + t] = f2bf(y0);
        OutB[(long)row * 512 + t + 256] = f2bf(y1);
    }
}

// ---------------------------------------------------------------------------
extern "C" void kernel_launch(void* const* d_in, const int* in_sizes, int n_in,
                              void* d_out, int out_size, void* d_ws, size_t ws_size,
                              hipStream_t stream) {
    const float* q  = (const float*)d_in[0];
    const float* k  = (const float*)d_in[1];
    const float* v  = (const float*)d_in[2];
    const float* Wq = (const float*)d_in[3];
    const float* Wk = (const float*)d_in[4];
    const float* Wv = (const float*)d_in[5];
    const float* Wm = (const float*)d_in[6];
    const float* W1 = (const float*)d_in[7];
    const float* W2 = (const float*)d_in[8];
    const float* g1 = (const float*)d_in[9];
    const float* b1 = (const float*)d_in[10];
    const float* g2 = (const float*)d_in[11];
    const float* b2 = (const float*)d_in[12];

    char* ws = (char*)d_ws;
    // workspace layout (bytes); high-water ~124MB
    u16* WTq = (u16*)(ws + 0);            // 512KB each
    u16* WTk = (u16*)(ws + 524288);
    u16* WTv = (u16*)(ws + 1048576);
    u16* WTm = (u16*)(ws + 1572864);
    u16* W1T = (u16*)(ws + 2097152);      // [2048,512] 2MB
    u16* W2T = (u16*)(ws + 4194304);      // [512,2048] 2MB
    u16* qc  = (u16*)(ws + 6291456);      // bf16 casts of q/k/v, 16.8MB each
    u16* kc  = (u16*)(ws + 23068672);
    u16* vc  = (u16*)(ws + 39845888);
    u16* Qb  = (u16*)(ws + 56623104);     // elu+1 projections
    u16* Kb  = (u16*)(ws + 73400320);
    u16* Vb  = (u16*)(ws + 90177536);
    float* KVb = (float*)(ws + 106954752); // 512KB
    float* KSb = (float*)(ws + 107479040); // 8KB
    u16* Msg = (u16*)(ws + 107487232);    // 16.8MB -> high-water 124264448
    float* Part = (float*)(ws + 23068672); // 33.5MB partial KV (kc/vc dead)
    float* KsPart = (float*)(ws + 6291456);// 512KB (qc dead after projections)
    float* xpre = (float*)(ws + 23068672); // 33.5MB (Part dead after reduce)
    u16* x1  = qc;                         // reuses qc (KsPart dead by LN1)
    u16* Hid = (u16*)(ws + 56623104);     // 67MB, reuses Qb..Msg (dead at FFN)

    // fp32 -> bf16 casts of activations
    f2b_k<<<dim3(8192), 256, 0, stream>>>(q, qc, 8388608);
    f2b_k<<<dim3(8192), 256, 0, stream>>>(k, kc, 8388608);
    f2b_k<<<dim3(8192), 256, 0, stream>>>(v, vc, 8388608);

    // weight transposes + cast ([in,out] fp32 -> [out,in] bf16)
    transpose_k<<<dim3(1024), 256, 0, stream>>>(Wq, WTq, 512, 512);
    transpose_k<<<dim3(1024), 256, 0, stream>>>(Wk, WTk, 512, 512);
    transpose_k<<<dim3(1024), 256, 0, stream>>>(Wv, WTv, 512, 512);
    transpose_k<<<dim3(1024), 256, 0, stream>>>(Wm, WTm, 512, 512);
    transpose_k<<<dim3(4096), 256, 0, stream>>>(W1, W1T, 512, 2048);
    transpose_k<<<dim3(4096), 256, 0, stream>>>(W2, W2T, 2048, 512);

    // projections with fused activation
    gemm_bt<<<dim3(4, 128), 256, 0, stream>>>(qc, WTq, Qb, nullptr, 16384, 512, 512, EPI_ELU1);
    gemm_bt<<<dim3(4, 128), 256, 0, stream>>>(kc, WTk, Kb, nullptr, 16384, 512, 512, EPI_ELU1);
    gemm_bt<<<dim3(4, 128), 256, 0, stream>>>(vc, WTv, Vb, nullptr, 16384, 512, 512, EPI_BF16);

    // linear attention: two-stage KV (no atomics), then msg
    kv_part<<<dim3(32, 64), 256, 0, stream>>>(Kb, Vb, Part, KsPart);
    kv_reduce<<<dim3(520), 256, 0, stream>>>(Part, KsPart, KVb, KSb);
    msg_k<<<dim3(32, 64), 256, 0, stream>>>(Qb, KVb, KSb, Msg);

    // merge + residual(q fp32) + LN1 (bf16 out for FFN input)
    gemm_bt<<<dim3(4, 128), 256, 0, stream>>>(Msg, WTm, xpre, q, 16384, 512, 512, EPI_ADDRES_F32);
    ln_k<<<dim3(16384), 256, 0, stream>>>(xpre, g1, b1, x1, nullptr, 0);

    // FFN + residual(q fp32) + LN2 (fp32 out -> d_out)
    gemm_bt<<<dim3(16, 128), 256, 0, stream>>>(x1, W1T, Hid, nullptr, 16384, 2048, 512, EPI_RELU);
    gemm_bt<<<dim3(4, 128), 256, 0, stream>>>(Hid, W2T, xpre, q, 16384, 512, 2048, EPI_ADDRES_F32);
    ln_k<<<dim3(16384), 256, 0, stream>>>(xpre, g2, b2, nullptr, (float*)d_out, 1);
}

// Round 7
// 570.829 us; speedup vs baseline: 1.0500x; 1.0217x over previous
//
#include <hip/hip_runtime.h>

typedef unsigned short u16;
typedef unsigned int u32;

typedef __bf16 bf16x8 __attribute__((ext_vector_type(8)));
typedef float f32x4 __attribute__((ext_vector_type(4)));

#define EPI_BF16 0
#define EPI_ELU1 1
#define EPI_RELU 2
#define EPI_ADDRES_F32 3
#define EPI_PROJ3 4

__device__ __forceinline__ float bf2f(u16 x) {
    u32 u = ((u32)x) << 16;
    return __uint_as_float(u);
}
__device__ __forceinline__ u16 f2bf(float f) {
    u32 u = __float_as_uint(f);
    u32 r = (u + 0x7FFFu + ((u >> 16) & 1u)) >> 16;
    return (u16)r;
}

// async global->LDS, 16B per lane; LDS dest = wave-uniform base + lane*16
__device__ __forceinline__ void gload_lds16(const u16* g, u16* l) {
    __builtin_amdgcn_global_load_lds(
        (const __attribute__((address_space(1))) u32*)g,
        (__attribute__((address_space(3))) u32*)l, 16, 0, 0);
}

// ---------------------------------------------------------------------------
// fp32 -> bf16 conversion (vectorized, 4 elems/thread)
// ---------------------------------------------------------------------------
__global__ __launch_bounds__(256) void f2b_k(const float* __restrict__ in,
                                             u16* __restrict__ out, int n) {
    int i = (blockIdx.x * 256 + threadIdx.x) * 4;
    if (i >= n) return;
    float4 f = *(const float4*)(in + i);
    ushort4 o;
    o.x = f2bf(f.x); o.y = f2bf(f.y); o.z = f2bf(f.z); o.w = f2bf(f.w);
    *(ushort4*)(out + i) = o;
}

// ---------------------------------------------------------------------------
// Weight transpose + cast: in fp32 [R][C] -> out bf16 [C][R]
// ---------------------------------------------------------------------------
__global__ void transpose_k(const float* __restrict__ in, u16* __restrict__ out,
                            int R, int C) {
    int idx = blockIdx.x * 256 + threadIdx.x;
    if (idx >= R * C) return;
    int c = idx / R, r = idx % R;        // out index = c*R + r
    out[idx] = f2bf(in[(long)r * C + c]);
}

// ---------------------------------------------------------------------------
// GEMM: C[M,N] = A[M,K] (bf16) @ Bt[N,K]^T (bf16), fp32 accum, fused epilogue.
// 128x128 tile, BK=32, 4 waves (2x2 of 64x64), mfma_f32_16x16x32_bf16.
//
// Round-7: REVERT to the r3 schedule (2-buffer, issue-next-tile-early,
// vmcnt(0)+__syncthreads per step) — rounds 4-6 proved counted-vmcnt +
// sched_barrier grafts REGRESS on this 1-barrier loop (74->95us; the guide's
// regime gate: T4 pays only inside 8-phase; m141: order-pinning defeats the
// compiler scheduler). KEEP two proven wins: (a) r4's conflict-free LDS
// layout [4 kgroups][128 rows][16B] (SQ_LDS_BANK_CONFLICT 4.19M -> 0),
// (b) XCD-chunked swizzle (FETCH 150 -> 57.5MB on FFN2).
//
// EPI_PROJ3: batched q/k/v projections in one dispatch (N=1536). qc/kc/vc
// and WTq/WTk/WTv are contiguous with uniform spacing, so third = n0>>9
// selects A tensor, B rows come from the concatenated WT block, and the
// epilogue writes Qb/Kb/Vb (+elu1 for thirds 0,1; plain bf16 for third 2).
// 1536 blocks = 5 blocks/CU co-resident (vs 3 sequential dispatches at 2/CU).
// ---------------------------------------------------------------------------
__global__ __launch_bounds__(256) void gemm_bt(
    const u16* __restrict__ A, const u16* __restrict__ Bt,
    void* __restrict__ C, const float* __restrict__ Res,
    int M, int N, int K, int epi)
{
    __shared__ __align__(16) u16 As[2][4096];   // 2 buffers x 8KB
    __shared__ __align__(16) u16 Bs[2][4096];

    int t = threadIdx.x;

    // XCD-chunked swizzle (bijective; all gemm grids are %8==0)
    int gx = gridDim.x;
    int nwg = gx * gridDim.y;
    int bid = blockIdx.y * gx + blockIdx.x;
    if ((nwg & 7) == 0) {
        int cpx = nwg >> 3;
        bid = (bid & 7) * cpx + (bid >> 3);
    }
    int m0 = (bid / gx) * 128, n0 = (bid % gx) * 128;

    int third = 0;
    if (epi == EPI_PROJ3) {              // batched projections: pick A tensor
        third = n0 >> 9;                 // 0:q 1:k 2:v (n-tile never straddles)
        A += (long)third * 8388608;      // qc/kc/vc spacing (u16 elems)
    }

    int wave = t >> 6, lane = t & 63;
    int wm = (wave >> 1) * 64, wn = (wave & 1) * 64;
    int lrow = lane & 15;
    int lg = lane >> 4;                  // k-group 0..3 (8 k-elems each)

    f32x4 acc[4][4] = {};

    // staging (r4-verified mapping): lane stages row srow for k-groups
    // (wave>>1) and (wave>>1)+2; dest slots wave*64+lane and +256 (16B units).
    int srow = (wave & 1) * 64 + lane;
    int sg8 = (wave >> 1) * 8;
    const u16* pA0 = A + (long)(m0 + srow) * K + sg8;
    const u16* pB0 = Bt + (long)(n0 + srow) * K + sg8;

    int nt = K >> 5;
    int cur = 0;

    // prologue: stage tile 0 into buffer 0
    {
        u16* a = As[0] + wave * 512;
        u16* b = Bs[0] + wave * 512;
        gload_lds16(pA0, a);
        gload_lds16(pA0 + 16, a + 2048);
        gload_lds16(pB0, b);
        gload_lds16(pB0 + 16, b + 2048);
    }
    __builtin_amdgcn_s_waitcnt(0);
    __syncthreads();

    for (int kt = 0; kt < nt; ++kt) {
        // issue next tile's loads into the other buffer (overlaps compute);
        // buffer cur^1 was last read in step kt-1, protected by that step's
        // barrier.
        if (kt + 1 < nt) {
            int k0 = (kt + 1) << 5;
            u16* a = As[cur ^ 1] + wave * 512;
            u16* b = Bs[cur ^ 1] + wave * 512;
            gload_lds16(pA0 + k0, a);
            gload_lds16(pA0 + k0 + 16, a + 2048);
            gload_lds16(pB0 + k0, b);
            gload_lds16(pB0 + k0 + 16, b + 2048);
        }

        const u16* As_c = As[cur] + lg * 1024;
        const u16* Bs_c = Bs[cur] + lg * 1024;
        bf16x8 af[4], bfr[4];
#pragma unroll
        for (int mi = 0; mi < 4; mi++)
            af[mi] = *(const bf16x8*)(As_c + (wm + mi * 16 + lrow) * 8);
#pragma unroll
        for (int ni = 0; ni < 4; ni++)
            bfr[ni] = *(const bf16x8*)(Bs_c + (wn + ni * 16 + lrow) * 8);
#pragma unroll
        for (int mi = 0; mi < 4; mi++)
#pragma unroll
            for (int ni = 0; ni < 4; ni++)
                acc[mi][ni] = __builtin_amdgcn_mfma_f32_16x16x32_bf16(
                    af[mi], bfr[ni], acc[mi][ni], 0, 0, 0);

        if (kt + 1 < nt) {
            __builtin_amdgcn_s_waitcnt(0);   // prefetch landed
            __syncthreads();                 // everyone done reading cur
            cur ^= 1;
        }
    }

    // Epilogue: D[row=(lane>>4)*4+r][col=lane&15] per 16x16 tile (verified m89/m91)
    int rq = (lane >> 4) * 4;
    int colb = n0 + wn + (lane & 15);
#pragma unroll
    for (int mi = 0; mi < 4; mi++) {
#pragma unroll
        for (int ni = 0; ni < 4; ni++) {
#pragma unroll
            for (int r = 0; r < 4; r++) {
                int row = m0 + wm + mi * 16 + rq + r;
                int col = colb + ni * 16;
                float v0 = acc[mi][ni][r];
                if (epi == EPI_PROJ3) {
                    // write to Qb/Kb/Vb (uniform spacing from C base)
                    u16* Cb = (u16*)C + (long)third * 8388608;
                    long idx = (long)row * 512 + (col - (third << 9));
                    float v = (third < 2)
                                  ? (v0 > 0.f ? v0 + 1.f : __expf(v0))
                                  : v0;
                    Cb[idx] = f2bf(v);
                } else {
                    long idx = (long)row * N + col;
                    if (epi == EPI_ELU1) {
                        float v = v0 > 0.f ? v0 + 1.f : __expf(v0);
                        ((u16*)C)[idx] = f2bf(v);
                    } else if (epi == EPI_RELU) {
                        ((u16*)C)[idx] = f2bf(v0 > 0.f ? v0 : 0.f);
                    } else if (epi == EPI_ADDRES_F32) {
                        ((float*)C)[idx] = v0 + Res[idx];
                    } else {
                        ((u16*)C)[idx] = f2bf(v0);
                    }
                }
            }
        }
    }
}

// ---------------------------------------------------------------------------
// KV stage 1: per (bh, s-split) partial KVp[d][v] = sum_s K[s,d]*V[s,v] and
// KsPart[d] = sum_s K[s,d]. Round-7: 32 splits x 128 s-rows (2 staged 64-row
// tiles per block). Part shrinks 134MB -> 16.8MB: the old 64-split version
// round-tripped 268MB of HBM for a 4-GFLOP computation (~40us of pure BW).
// Summation order over s stays globally ascending -> bit-identical KV.
// grid (32, 32), 256 threads.
// ---------------------------------------------------------------------------
__global__ __launch_bounds__(256) void kv_part(
    const u16* __restrict__ Kf, const u16* __restrict__ Vf,
    float* __restrict__ Part, float* __restrict__ KsPart)
{
    __shared__ float sKf[64 * 68];   // stride 68: conflict-light, 16B aligned
    __shared__ float sVf[64 * 68];
    int bh = blockIdx.x;
    int b = bh >> 3, h = bh & 7;
    int t = threadIdx.x;
    int d = t & 63, vg = t >> 6;

    float acc[16] = {};
    float ks = 0.f;

    for (int st = 0; st < 2; ++st) {
        int s0 = blockIdx.y * 128 + st * 64;
        {   // stage FULL 64x64 K and V tiles, bf16 -> fp32 (256 thr x 16 elems)
            int row = t >> 2, c16 = (t & 3) * 16;
            long g = ((long)b * 4096 + s0 + row) * 512 + h * 64 + c16;
            uint4 kk0 = *(const uint4*)(Kf + g);
            uint4 kk1 = *(const uint4*)(Kf + g + 8);
            uint4 vv0 = *(const uint4*)(Vf + g);
            uint4 vv1 = *(const uint4*)(Vf + g + 8);
            float* dk = sKf + row * 68 + c16;
            float* dv = sVf + row * 68 + c16;
            u32 kw[8] = {kk0.x, kk0.y, kk0.z, kk0.w, kk1.x, kk1.y, kk1.z, kk1.w};
            u32 vw[8] = {vv0.x, vv0.y, vv0.z, vv0.w, vv1.x, vv1.y, vv1.z, vv1.w};
#pragma unroll
            for (int j = 0; j < 8; j++) {
                dk[2 * j]     = __uint_as_float(kw[j] << 16);
                dk[2 * j + 1] = __uint_as_float(kw[j] & 0xFFFF0000u);
                dv[2 * j]     = __uint_as_float(vw[j] << 16);
                dv[2 * j + 1] = __uint_as_float(vw[j] & 0xFFFF0000u);
            }
        }
        __syncthreads();

#pragma unroll 4
        for (int s = 0; s < 64; s++) {
            float kd = sKf[s * 68 + d];
            if (vg == 0) ks += kd;                    // wave-uniform branch
            const float* vr = sVf + s * 68 + vg * 16; // wave-uniform -> broadcast
            float4 v0 = *(const float4*)(vr);
            float4 v1 = *(const float4*)(vr + 4);
            float4 v2 = *(const float4*)(vr + 8);
            float4 v3 = *(const float4*)(vr + 12);
            acc[0]  += kd * v0.x; acc[1]  += kd * v0.y;
            acc[2]  += kd * v0.z; acc[3]  += kd * v0.w;
            acc[4]  += kd * v1.x; acc[5]  += kd * v1.y;
            acc[6]  += kd * v1.z; acc[7]  += kd * v1.w;
            acc[8]  += kd * v2.x; acc[9]  += kd * v2.y;
            acc[10] += kd * v2.z; acc[11] += kd * v2.w;
            acc[12] += kd * v3.x; acc[13] += kd * v3.y;
            acc[14] += kd * v3.z; acc[15] += kd * v3.w;
        }
        __syncthreads();   // WAR: done reading before next stage overwrites
    }

    float* pp = Part + ((long)bh * 32 + blockIdx.y) * 4096 + d * 64 + vg * 16;
#pragma unroll
    for (int j = 0; j < 16; j++) pp[j] = acc[j];
    if (vg == 0) KsPart[((bh * 32) + blockIdx.y) * 64 + d] = ks;
}

// ---------------------------------------------------------------------------
// KV stage 2: KV[bh][dv] = sum over 32 splits; Ksum folded into tail blocks.
// grid 520 x 256: idx<131072 -> KV, else -> Ksum (2048 entries).
// ---------------------------------------------------------------------------
__global__ __launch_bounds__(256) void kv_reduce(
    const float* __restrict__ Part, const float* __restrict__ KsPart,
    float* __restrict__ KV, float* __restrict__ Ksum)
{
    int i = blockIdx.x * 256 + threadIdx.x;
    if (i < 131072) {
        int bh = i >> 12, dv = i & 4095;
        const float* p = Part + (long)bh * 32 * 4096 + dv;
        float s = 0.f;
#pragma unroll 8
        for (int sp = 0; sp < 32; sp++) s += p[(long)sp * 4096];
        KV[i] = s;
    } else if (i < 133120) {
        int j = i - 131072;
        int bh = j >> 6, d = j & 63;
        const float* p = KsPart + bh * 32 * 64 + d;
        float s = 0.f;
#pragma unroll 8
        for (int sp = 0; sp < 32; sp++) s += p[sp * 64];
        Ksum[j] = s;
    }
}

// ---------------------------------------------------------------------------
// msg[b,l,h,v] = (sum_d Q[b,l,h,d]*KV[bh][d][v]) / (Q . Ksum + eps)
// lane = v; KV column in 64 VGPRs (from LDS-transposed copy); Q rows read as
// wave-uniform ds_read_b128 broadcasts; Z precomputed per row. All fp32.
// ---------------------------------------------------------------------------
__global__ __launch_bounds__(256) void msg_k(
    const u16* __restrict__ Q, const float* __restrict__ KV,
    const float* __restrict__ Ksum, u16* __restrict__ Msg)
{
    __shared__ float sKVt[64 * 68];  // [v][d], pad 68 (stride%32==4 -> 2-way max)
    __shared__ float sQ[64 * 68];    // [l_local][d] fp32
    __shared__ float sKs[64];
    __shared__ float sZ[64];

    int bh = blockIdx.x;
    int b = bh >> 3, h = bh & 7;
    int l0 = blockIdx.y * 64;
    int t = threadIdx.x, wave = t >> 6, lane = t & 63;

    {   // stage KV[bh] (fp32 [d][v]) -> sKVt[v][d] (transposed). 16 elems/thr.
        const float* src = KV + (long)bh * 4096 + t * 16;
        int d = t >> 2;              // source row (d index)
        int v0 = (t & 3) * 16;       // source col base (v index)
        float4 a0 = *(const float4*)(src);
        float4 a1 = *(const float4*)(src + 4);
        float4 a2 = *(const float4*)(src + 8);
        float4 a3 = *(const float4*)(src + 12);
        float tmp[16] = {a0.x, a0.y, a0.z, a0.w, a1.x, a1.y, a1.z, a1.w,
                         a2.x, a2.y, a2.z, a2.w, a3.x, a3.y, a3.z, a3.w};
#pragma unroll
        for (int j = 0; j < 16; j++) sKVt[(v0 + j) * 68 + d] = tmp[j];
    }
    {   // stage Q tile rows l0..l0+63 (bf16 -> fp32). 16 elems/thr.
        int row = t >> 2, c = (t & 3) * 16;
        const u16* src = Q + ((long)b * 4096 + l0 + row) * 512 + h * 64 + c;
        uint4 q0 = *(const uint4*)(src);
        uint4 q1 = *(const uint4*)(src + 8);
        float* dq = sQ + row * 68 + c;
        u32 qw[8] = {q0.x, q0.y, q0.z, q0.w, q1.x, q1.y, q1.z, q1.w};
#pragma unroll
        for (int j = 0; j < 8; j++) {
            dq[2 * j]     = __uint_as_float(qw[j] << 16);
            dq[2 * j + 1] = __uint_as_float(qw[j] & 0xFFFF0000u);
        }
    }
    if (t < 64) sKs[t] = Ksum[bh * 64 + t];
    __syncthreads();

    // hoist this lane's KV column into registers (one-time, 16x ds_read_b128)
    float kv[64];
    {
        const float* kr = sKVt + lane * 68;
#pragma unroll
        for (int j = 0; j < 16; j++) {
            float4 x = *(const float4*)(kr + 4 * j);
            kv[4 * j]     = x.x; kv[4 * j + 1] = x.y;
            kv[4 * j + 2] = x.z; kv[4 * j + 3] = x.w;
        }
    }
    // per-row normalizer (wave 0 only; sKs reads are uniform -> broadcast)
    if (t < 64) {
        const float* qr = sQ + t * 68;
        float zp = 0.f;
#pragma unroll
        for (int d = 0; d < 64; d++) zp += qr[d] * sKs[d];
        sZ[t] = 1.f / (zp + 1e-6f);
    }
    __syncthreads();

    const long obase = ((long)b * 4096 + l0) * 512 + h * 64 + lane;
    int lbase = wave * 16;
#pragma unroll 4
    for (int i = 0; i < 16; i++) {
        int ll = lbase + i;
        const float* qr = sQ + ll * 68;
        float a0 = 0.f, a1 = 0.f, a2 = 0.f, a3 = 0.f;  // 4 indep chains
#pragma unroll
        for (int db = 0; db < 16; db++) {
            float4 q4 = *(const float4*)(qr + 4 * db);  // wave-uniform bcast
            a0 += q4.x * kv[4 * db];
            a1 += q4.y * kv[4 * db + 1];
            a2 += q4.z * kv[4 * db + 2];
            a3 += q4.w * kv[4 * db + 3];
        }
        float acc = (a0 + a1) + (a2 + a3);
        Msg[obase + (long)ll * 512] = f2bf(acc * sZ[ll]);
    }
}

// ---------------------------------------------------------------------------
// LayerNorm over 512 cols, fp32 input, fp32 gamma/beta.
// out_f32 != 0 -> write fp32 to OutF, else bf16 to OutB.
// ---------------------------------------------------------------------------
__global__ __launch_bounds__(256) void ln_k(
    const float* __restrict__ X, const float* __restrict__ g,
    const float* __restrict__ bta, u16* __restrict__ OutB,
    float* __restrict__ OutF, int out_f32)
{
    int row = blockIdx.x;
    const float* x = X + (long)row * 512;
    int t = threadIdx.x;
    float x0 = x[t], x1 = x[t + 256];
    float s = x0 + x1, sq = x0 * x0 + x1 * x1;
#pragma unroll
    for (int off = 32; off > 0; off >>= 1) {
        s += __shfl_xor(s, off, 64);
        sq += __shfl_xor(sq, off, 64);
    }
    __shared__ float rs[4], rq[4];
    int wave = t >> 6, lane = t & 63;
    if (lane == 0) { rs[wave] = s; rq[wave] = sq; }
    __syncthreads();
    s = rs[0] + rs[1] + rs[2] + rs[3];
    sq = rq[0] + rq[1] + rq[2] + rq[3];
    float mu = s * (1.f / 512.f);
    float var = sq * (1.f / 512.f) - mu * mu;
    float rstd = rsqrtf(var + 1e-5f);
    float y0 = (x0 - mu) * rstd * g[t] + bta[t];
    float y1 = (x1 - mu) * rstd * g[t + 256] + bta[t + 256];
    if (out_f32) {
        OutF[(long)row * 512 + t] = y0;
        OutF[(long)row * 512 + t + 256] = y1;
    } else {
        OutB[(long)row * 512 + t] = f2bf(y0);
        OutB[(long)row * 512 + t + 256] = f2bf(y1);
    }
}

// ---------------------------------------------------------------------------
extern "C" void kernel_launch(void* const* d_in, const int* in_sizes, int n_in,
                              void* d_out, int out_size, void* d_ws, size_t ws_size,
                              hipStream_t stream) {
    const float* q  = (const float*)d_in[0];
    const float* k  = (const float*)d_in[1];
    const float* v  = (const float*)d_in[2];
    const float* Wq = (const float*)d_in[3];
    const float* Wk = (const float*)d_in[4];
    const float* Wv = (const float*)d_in[5];
    const float* Wm = (const float*)d_in[6];
    const float* W1 = (const float*)d_in[7];
    const float* W2 = (const float*)d_in[8];
    const float* g1 = (const float*)d_in[9];
    const float* b1 = (const float*)d_in[10];
    const float* g2 = (const float*)d_in[11];
    const float* b2 = (const float*)d_in[12];

    char* ws = (char*)d_ws;
    // workspace layout (bytes); high-water ~124MB
    u16* WTq = (u16*)(ws + 0);            // 512KB each; WTq|WTk|WTv contiguous
    u16* WTk = (u16*)(ws + 524288);
    u16* WTv = (u16*)(ws + 1048576);
    u16* WTm = (u16*)(ws + 1572864);
    u16* W1T = (u16*)(ws + 2097152);      // [2048,512] 2MB
    u16* W2T = (u16*)(ws + 4194304);      // [512,2048] 2MB
    u16* qc  = (u16*)(ws + 6291456);      // bf16 casts, CONTIGUOUS 16.8MB each
    u16* kc  = (u16*)(ws + 23068672);
    u16* vc  = (u16*)(ws + 39845888);
    u16* Qb  = (u16*)(ws + 56623104);     // projections, CONTIGUOUS 16.8MB each
    u16* Kb  = (u16*)(ws + 73400320);
    u16* Vb  = (u16*)(ws + 90177536);
    float* KVb = (float*)(ws + 106954752); // 512KB
    float* KSb = (float*)(ws + 107479040); // 8KB
    u16* Msg = (u16*)(ws + 107487232);    // 16.8MB -> high-water 124264448
    float* Part = (float*)(ws + 23068672); // 16.8MB partial KV (kc/vc dead)
    float* KsPart = (float*)(ws + 6291456);// 256KB (qc dead after projections)
    float* xpre = (float*)(ws + 23068672); // 33.5MB (Part dead after reduce)
    u16* x1  = qc;                         // reuses qc (KsPart dead by LN1)
    u16* Hid = (u16*)(ws + 56623104);     // 67MB, reuses Qb..Msg (dead at FFN)

    // fp32 -> bf16 casts of activations
    f2b_k<<<dim3(8192), 256, 0, stream>>>(q, qc, 8388608);
    f2b_k<<<dim3(8192), 256, 0, stream>>>(k, kc, 8388608);
    f2b_k<<<dim3(8192), 256, 0, stream>>>(v, vc, 8388608);

    // weight transposes + cast ([in,out] fp32 -> [out,in] bf16)
    transpose_k<<<dim3(1024), 256, 0, stream>>>(Wq, WTq, 512, 512);
    transpose_k<<<dim3(1024), 256, 0, stream>>>(Wk, WTk, 512, 512);
    transpose_k<<<dim3(1024), 256, 0, stream>>>(Wv, WTv, 512, 512);
    transpose_k<<<dim3(1024), 256, 0, stream>>>(Wm, WTm, 512, 512);
    transpose_k<<<dim3(4096), 256, 0, stream>>>(W1, W1T, 512, 2048);
    transpose_k<<<dim3(4096), 256, 0, stream>>>(W2, W2T, 2048, 512);

    // batched q/k/v projections: one dispatch, N=1536 (A and C offset by
    // n0>>9 inside; elu1 fused for q,k; plain bf16 for v). 1536 blocks.
    gemm_bt<<<dim3(12, 128), 256, 0, stream>>>(qc, WTq, Qb, nullptr, 16384, 1536, 512, EPI_PROJ3);

    // linear attention: two-stage KV (no atomics), then msg
    kv_part<<<dim3(32, 32), 256, 0, stream>>>(Kb, Vb, Part, KsPart);
    kv_reduce<<<dim3(520), 256, 0, stream>>>(Part, KsPart, KVb, KSb);
    msg_k<<<dim3(32, 64), 256, 0, stream>>>(Qb, KVb, KSb, Msg);

    // merge + residual(q fp32) + LN1 (bf16 out for FFN input)
    gemm_bt<<<dim3(4, 128), 256, 0, stream>>>(Msg, WTm, xpre, q, 16384, 512, 512, EPI_ADDRES_F32);
    ln_k<<<dim3(16384), 256, 0, stream>>>(xpre, g1, b1, x1, nullptr, 0);

    // FFN + residual(q fp32) + LN2 (fp32 out -> d_out)
    gemm_bt<<<dim3(16, 128), 256, 0, stream>>>(x1, W1T, Hid, nullptr, 16384, 2048, 512, EPI_RELU);
    gemm_bt<<<dim3(4, 128), 256, 0, stream>>>(Hid, W2T, xpre, q, 16384, 512, 2048, EPI_ADDRES_F32);
    ln_k<<<dim3(16384), 256, 0, stream>>>(xpre, g2, b2, nullptr, (float*)d_out, 1);
}

// Round 8
// 509.589 us; speedup vs baseline: 1.1762x; 1.1202x over previous
//
#include <hip/hip_runtime.h>

typedef unsigned short u16;
typedef unsigned int u32;

typedef __bf16 bf16x8 __attribute__((ext_vector_type(8)));
typedef float f32x4 __attribute__((ext_vector_type(4)));

#define EPI_BF16 0
#define EPI_ELU1 1
#define EPI_RELU 2
#define EPI_ADDRES_F32 3
#define EPI_PROJ3 4

__device__ __forceinline__ float bf2f(u16 x) {
    u32 u = ((u32)x) << 16;
    return __uint_as_float(u);
}
__device__ __forceinline__ u16 f2bf(float f) {
    u32 u = __float_as_uint(f);
    u32 r = (u + 0x7FFFu + ((u >> 16) & 1u)) >> 16;
    return (u16)r;
}

// async global->LDS, 16B per lane; LDS dest = wave-uniform base + lane*16
__device__ __forceinline__ void gload_lds16(const u16* g, u16* l) {
    __builtin_amdgcn_global_load_lds(
        (const __attribute__((address_space(1))) u32*)g,
        (__attribute__((address_space(3))) u32*)l, 16, 0, 0);
}

// ---------------------------------------------------------------------------
// fp32 -> bf16 conversion (vectorized, 4 elems/thread)
// ---------------------------------------------------------------------------
__global__ __launch_bounds__(256) void f2b_k(const float* __restrict__ in,
                                             u16* __restrict__ out, int n) {
    int i = (blockIdx.x * 256 + threadIdx.x) * 4;
    if (i >= n) return;
    float4 f = *(const float4*)(in + i);
    ushort4 o;
    o.x = f2bf(f.x); o.y = f2bf(f.y); o.z = f2bf(f.z); o.w = f2bf(f.w);
    *(ushort4*)(out + i) = o;
}

// ---------------------------------------------------------------------------
// Weight transpose + cast: in fp32 [R][C] -> out bf16 [C][R]
// ---------------------------------------------------------------------------
__global__ void transpose_k(const float* __restrict__ in, u16* __restrict__ out,
                            int R, int C) {
    int idx = blockIdx.x * 256 + threadIdx.x;
    if (idx >= R * C) return;
    int c = idx / R, r = idx % R;        // out index = c*R + r
    out[idx] = f2bf(in[(long)r * C + c]);
}

// ---------------------------------------------------------------------------
// GEMM: C[M,N] = A[M,K] (bf16) @ Bt[N,K]^T (bf16), fp32 accum, fused epilogue.
// 128x128 tile, BK=32, 4 waves (2x2 of 64x64), mfma_f32_16x16x32_bf16.
//
// Round-8: r3 schedule (2-buf, issue-early, vmcnt(0)+__syncthreads) with the
// rule-#21 BOTH-SIDES XOR swizzle. r7 post-mortem: the [kgroup][row] layout
// fixed read conflicts (4.19M->0) but scattered the DMA *source* (consecutive
// lanes -> consecutive ROWS, 64 cachelines/instr vs r3's 16) -> FFN2 74->97us.
// Fix: row-major [128][32] LDS with chunk index XOR'd by (row>>2)&3:
//   - staging keeps r3's coalesced 4-lanes-per-row source; the XOR only
//     permutes WHICH 16B chunk of the same 64B segment each lane fetches
//     (same address set -> same coalescing). (row>>2)&3 == lane>>4 for this
//     mapping, both staging calls.
//   - read uses kx = (lg ^ (lrow>>2))*8: per 16-lane quarter each 4-bank
//     group is hit exactly 2x -> conflict-free (2-way free, m136); unswizzled
//     r3 was 8-way (4.19M cycles, ~9%).
// Pure placement permutation -> MFMA operands bit-identical.
// XCD-chunked swizzle kept (FETCH 150->57.5MB on FFN2).
//
// EPI_PROJ3: batched q/k/v projections in one dispatch (N=1536); third=n0>>9
// picks the A tensor and output buffer; elu1 fused for thirds 0,1.
// ---------------------------------------------------------------------------
__global__ __launch_bounds__(256) void gemm_bt(
    const u16* __restrict__ A, const u16* __restrict__ Bt,
    void* __restrict__ C, const float* __restrict__ Res,
    int M, int N, int K, int epi)
{
    __shared__ __align__(16) u16 As[2][4096];   // 2 buffers x 8KB, row-major [128][32]
    __shared__ __align__(16) u16 Bs[2][4096];

    int t = threadIdx.x;

    // XCD-chunked swizzle (bijective; all gemm grids are %8==0)
    int gx = gridDim.x;
    int nwg = gx * gridDim.y;
    int bid = blockIdx.y * gx + blockIdx.x;
    if ((nwg & 7) == 0) {
        int cpx = nwg >> 3;
        bid = (bid & 7) * cpx + (bid >> 3);
    }
    int m0 = (bid / gx) * 128, n0 = (bid % gx) * 128;

    int third = 0;
    if (epi == EPI_PROJ3) {              // batched projections: pick A tensor
        third = n0 >> 9;                 // 0:q 1:k 2:v (n-tile never straddles)
        A += (long)third * 8388608;      // qc/kc/vc spacing (u16 elems)
    }

    int wave = t >> 6, lane = t & 63;
    int wm = (wave >> 1) * 64, wn = (wave & 1) * 64;
    int lrow = lane & 15;
    int kx = ((lane >> 4) ^ (lrow >> 2)) * 8;  // XOR-swizzled k-chunk (u16)

    f32x4 acc[4][4] = {};

    // staging: r3 coalesced mapping (lane l -> row w*16+(l>>2), 4 lanes/row)
    // with the matching source-chunk XOR: chunk = (l&3) ^ (l>>4).
    int srow = wave * 16 + (lane >> 2);
    int scol = ((lane & 3) ^ (lane >> 4)) * 8;
    const u16* pA0 = A + (long)(m0 + srow) * K + scol;
    const u16* pB0 = Bt + (long)(n0 + srow) * K + scol;
    const long s64 = (long)64 * K;

    int nt = K >> 5;
    int cur = 0;

    // prologue: stage tile 0 into buffer 0
    {
        u16* a = As[0] + wave * 512;
        u16* b = Bs[0] + wave * 512;
        gload_lds16(pA0, a);
        gload_lds16(pA0 + s64, a + 2048);
        gload_lds16(pB0, b);
        gload_lds16(pB0 + s64, b + 2048);
    }
    __builtin_amdgcn_s_waitcnt(0);
    __syncthreads();

    for (int kt = 0; kt < nt; ++kt) {
        // issue next tile's loads into the other buffer (overlaps compute);
        // buffer cur^1 was last read in step kt-1, protected by that barrier.
        if (kt + 1 < nt) {
            int k0 = (kt + 1) << 5;
            u16* a = As[cur ^ 1] + wave * 512;
            u16* b = Bs[cur ^ 1] + wave * 512;
            gload_lds16(pA0 + k0, a);
            gload_lds16(pA0 + s64 + k0, a + 2048);
            gload_lds16(pB0 + k0, b);
            gload_lds16(pB0 + s64 + k0, b + 2048);
        }

        const u16* As_c = As[cur];
        const u16* Bs_c = Bs[cur];
        bf16x8 af[4], bfr[4];
#pragma unroll
        for (int mi = 0; mi < 4; mi++)
            af[mi] = *(const bf16x8*)(As_c + (wm + mi * 16 + lrow) * 32 + kx);
#pragma unroll
        for (int ni = 0; ni < 4; ni++)
            bfr[ni] = *(const bf16x8*)(Bs_c + (wn + ni * 16 + lrow) * 32 + kx);
#pragma unroll
        for (int mi = 0; mi < 4; mi++)
#pragma unroll
            for (int ni = 0; ni < 4; ni++)
                acc[mi][ni] = __builtin_amdgcn_mfma_f32_16x16x32_bf16(
                    af[mi], bfr[ni], acc[mi][ni], 0, 0, 0);

        if (kt + 1 < nt) {
            __builtin_amdgcn_s_waitcnt(0);   // prefetch landed
            __syncthreads();                 // everyone done reading cur
            cur ^= 1;
        }
    }

    // Epilogue: D[row=(lane>>4)*4+r][col=lane&15] per 16x16 tile (verified m89/m91)
    int rq = (lane >> 4) * 4;
    int colb = n0 + wn + (lane & 15);
#pragma unroll
    for (int mi = 0; mi < 4; mi++) {
#pragma unroll
        for (int ni = 0; ni < 4; ni++) {
#pragma unroll
            for (int r = 0; r < 4; r++) {
                int row = m0 + wm + mi * 16 + rq + r;
                int col = colb + ni * 16;
                float v0 = acc[mi][ni][r];
                if (epi == EPI_PROJ3) {
                    // write to Qb/Kb/Vb (uniform spacing from C base)
                    u16* Cb = (u16*)C + (long)third * 8388608;
                    long idx = (long)row * 512 + (col - (third << 9));
                    float v = (third < 2)
                                  ? (v0 > 0.f ? v0 + 1.f : __expf(v0))
                                  : v0;
                    Cb[idx] = f2bf(v);
                } else {
                    long idx = (long)row * N + col;
                    if (epi == EPI_ELU1) {
                        float v = v0 > 0.f ? v0 + 1.f : __expf(v0);
                        ((u16*)C)[idx] = f2bf(v);
                    } else if (epi == EPI_RELU) {
                        ((u16*)C)[idx] = f2bf(v0 > 0.f ? v0 : 0.f);
                    } else if (epi == EPI_ADDRES_F32) {
                        ((float*)C)[idx] = v0 + Res[idx];
                    } else {
                        ((u16*)C)[idx] = f2bf(v0);
                    }
                }
            }
        }
    }
}

// ---------------------------------------------------------------------------
// KV stage 1: per (bh, s-split) partial KVp[d][v] = sum_s K[s,d]*V[s,v] and
// KsPart[d] = sum_s K[s,d]. 32 splits x 128 s-rows (2 staged 64-row tiles per
// block); Part = 16.8MB (vs 134MB at 64 splits). Ascending s order ->
// bit-identical KV. grid (32, 32), 256 threads.
// ---------------------------------------------------------------------------
__global__ __launch_bounds__(256) void kv_part(
    const u16* __restrict__ Kf, const u16* __restrict__ Vf,
    float* __restrict__ Part, float* __restrict__ KsPart)
{
    __shared__ float sKf[64 * 68];   // stride 68: conflict-light, 16B aligned
    __shared__ float sVf[64 * 68];
    int bh = blockIdx.x;
    int b = bh >> 3, h = bh & 7;
    int t = threadIdx.x;
    int d = t & 63, vg = t >> 6;

    float acc[16] = {};
    float ks = 0.f;

    for (int st = 0; st < 2; ++st) {
        int s0 = blockIdx.y * 128 + st * 64;
        {   // stage FULL 64x64 K and V tiles, bf16 -> fp32 (256 thr x 16 elems)
            int row = t >> 2, c16 = (t & 3) * 16;
            long g = ((long)b * 4096 + s0 + row) * 512 + h * 64 + c16;
            uint4 kk0 = *(const uint4*)(Kf + g);
            uint4 kk1 = *(const uint4*)(Kf + g + 8);
            uint4 vv0 = *(const uint4*)(Vf + g);
            uint4 vv1 = *(const uint4*)(Vf + g + 8);
            float* dk = sKf + row * 68 + c16;
            float* dv = sVf + row * 68 + c16;
            u32 kw[8] = {kk0.x, kk0.y, kk0.z, kk0.w, kk1.x, kk1.y, kk1.z, kk1.w};
            u32 vw[8] = {vv0.x, vv0.y, vv0.z, vv0.w, vv1.x, vv1.y, vv1.z, vv1.w};
#pragma unroll
            for (int j = 0; j < 8; j++) {
                dk[2 * j]     = __uint_as_float(kw[j] << 16);
                dk[2 * j + 1] = __uint_as_float(kw[j] & 0xFFFF0000u);
                dv[2 * j]     = __uint_as_float(vw[j] << 16);
                dv[2 * j + 1] = __uint_as_float(vw[j] & 0xFFFF0000u);
            }
        }
        __syncthreads();

#pragma unroll 4
        for (int s = 0; s < 64; s++) {
            float kd = sKf[s * 68 + d];
            if (vg == 0) ks += kd;                    // wave-uniform branch
            const float* vr = sVf + s * 68 + vg * 16; // wave-uniform -> broadcast
            float4 v0 = *(const float4*)(vr);
            float4 v1 = *(const float4*)(vr + 4);
            float4 v2 = *(const float4*)(vr + 8);
            float4 v3 = *(const float4*)(vr + 12);
            acc[0]  += kd * v0.x; acc[1]  += kd * v0.y;
            acc[2]  += kd * v0.z; acc[3]  += kd * v0.w;
            acc[4]  += kd * v1.x; acc[5]  += kd * v1.y;
            acc[6]  += kd * v1.z; acc[7]  += kd * v1.w;
            acc[8]  += kd * v2.x; acc[9]  += kd * v2.y;
            acc[10] += kd * v2.z; acc[11] += kd * v2.w;
            acc[12] += kd * v3.x; acc[13] += kd * v3.y;
            acc[14] += kd * v3.z; acc[15] += kd * v3.w;
        }
        __syncthreads();   // WAR: done reading before next stage overwrites
    }

    float* pp = Part + ((long)bh * 32 + blockIdx.y) * 4096 + d * 64 + vg * 16;
#pragma unroll
    for (int j = 0; j < 16; j++) pp[j] = acc[j];
    if (vg == 0) KsPart[((bh * 32) + blockIdx.y) * 64 + d] = ks;
}

// ---------------------------------------------------------------------------
// KV stage 2: KV[bh][dv] = sum over 32 splits; Ksum folded into tail blocks.
// grid 520 x 256: idx<131072 -> KV, else -> Ksum (2048 entries).
// ---------------------------------------------------------------------------
__global__ __launch_bounds__(256) void kv_reduce(
    const float* __restrict__ Part, const float* __restrict__ KsPart,
    float* __restrict__ KV, float* __restrict__ Ksum)
{
    int i = blockIdx.x * 256 + threadIdx.x;
    if (i < 131072) {
        int bh = i >> 12, dv = i & 4095;
        const float* p = Part + (long)bh * 32 * 4096 + dv;
        float s = 0.f;
#pragma unroll 8
        for (int sp = 0; sp < 32; sp++) s += p[(long)sp * 4096];
        KV[i] = s;
    } else if (i < 133120) {
        int j = i - 131072;
        int bh = j >> 6, d = j & 63;
        const float* p = KsPart + bh * 32 * 64 + d;
        float s = 0.f;
#pragma unroll 8
        for (int sp = 0; sp < 32; sp++) s += p[sp * 64];
        Ksum[j] = s;
    }
}

// ---------------------------------------------------------------------------
// msg[b,l,h,v] = (sum_d Q[b,l,h,d]*KV[bh][d][v]) / (Q . Ksum + eps)
// lane = v; KV column in 64 VGPRs (from LDS-transposed copy); Q rows read as
// wave-uniform ds_read_b128 broadcasts; Z precomputed per row. All fp32.
// ---------------------------------------------------------------------------
__global__ __launch_bounds__(256) void msg_k(
    const u16* __restrict__ Q, const float* __restrict__ KV,
    const float* __restrict__ Ksum, u16* __restrict__ Msg)
{
    __shared__ float sKVt[64 * 68];  // [v][d], pad 68 (stride%32==4 -> 2-way max)
    __shared__ float sQ[64 * 68];    // [l_local][d] fp32
    __shared__ float sKs[64];
    __shared__ float sZ[64];

    int bh = blockIdx.x;
    int b = bh >> 3, h = bh & 7;
    int l0 = blockIdx.y * 64;
    int t = threadIdx.x, wave = t >> 6, lane = t & 63;

    {   // stage KV[bh] (fp32 [d][v]) -> sKVt[v][d] (transposed). 16 elems/thr.
        const float* src = KV + (long)bh * 4096 + t * 16;
        int d = t >> 2;              // source row (d index)
        int v0 = (t & 3) * 16;       // source col base (v index)
        float4 a0 = *(const float4*)(src);
        float4 a1 = *(const float4*)(src + 4);
        float4 a2 = *(const float4*)(src + 8);
        float4 a3 = *(const float4*)(src + 12);
        float tmp[16] = {a0.x, a0.y, a0.z, a0.w, a1.x, a1.y, a1.z, a1.w,
                         a2.x, a2.y, a2.z, a2.w, a3.x, a3.y, a3.z, a3.w};
#pragma unroll
        for (int j = 0; j < 16; j++) sKVt[(v0 + j) * 68 + d] = tmp[j];
    }
    {   // stage Q tile rows l0..l0+63 (bf16 -> fp32). 16 elems/thr.
        int row = t >> 2, c = (t & 3) * 16;
        const u16* src = Q + ((long)b * 4096 + l0 + row) * 512 + h * 64 + c;
        uint4 q0 = *(const uint4*)(src);
        uint4 q1 = *(const uint4*)(src + 8);
        float* dq = sQ + row * 68 + c;
        u32 qw[8] = {q0.x, q0.y, q0.z, q0.w, q1.x, q1.y, q1.z, q1.w};
#pragma unroll
        for (int j = 0; j < 8; j++) {
            dq[2 * j]     = __uint_as_float(qw[j] << 16);
            dq[2 * j + 1] = __uint_as_float(qw[j] & 0xFFFF0000u);
        }
    }
    if (t < 64) sKs[t] = Ksum[bh * 64 + t];
    __syncthreads();

    // hoist this lane's KV column into registers (one-time, 16x ds_read_b128)
    float kv[64];
    {
        const float* kr = sKVt + lane * 68;
#pragma unroll
        for (int j = 0; j < 16; j++) {
            float4 x = *(const float4*)(kr + 4 * j);
            kv[4 * j]     = x.x; kv[4 * j + 1] = x.y;
            kv[4 * j + 2] = x.z; kv[4 * j + 3] = x.w;
        }
    }
    // per-row normalizer (wave 0 only; sKs reads are uniform -> broadcast)
    if (t < 64) {
        const float* qr = sQ + t * 68;
        float zp = 0.f;
#pragma unroll
        for (int d = 0; d < 64; d++) zp += qr[d] * sKs[d];
        sZ[t] = 1.f / (zp + 1e-6f);
    }
    __syncthreads();

    const long obase = ((long)b * 4096 + l0) * 512 + h * 64 + lane;
    int lbase = wave * 16;
#pragma unroll 4
    for (int i = 0; i < 16; i++) {
        int ll = lbase + i;
        const float* qr = sQ + ll * 68;
        float a0 = 0.f, a1 = 0.f, a2 = 0.f, a3 = 0.f;  // 4 indep chains
#pragma unroll
        for (int db = 0; db < 16; db++) {
            float4 q4 = *(const float4*)(qr + 4 * db);  // wave-uniform bcast
            a0 += q4.x * kv[4 * db];
            a1 += q4.y * kv[4 * db + 1];
            a2 += q4.z * kv[4 * db + 2];
            a3 += q4.w * kv[4 * db + 3];
        }
        float acc = (a0 + a1) + (a2 + a3);
        Msg[obase + (long)ll * 512] = f2bf(acc * sZ[ll]);
    }
}

// ---------------------------------------------------------------------------
// LayerNorm over 512 cols, fp32 input, fp32 gamma/beta.
// out_f32 != 0 -> write fp32 to OutF, else bf16 to OutB.
// ---------------------------------------------------------------------------
__global__ __launch_bounds__(256) void ln_k(
    const float* __restrict__ X, const float* __restrict__ g,
    const float* __restrict__ bta, u16* __restrict__ OutB,
    float* __restrict__ OutF, int out_f32)
{
    int row = blockIdx.x;
    const float* x = X + (long)row * 512;
    int t = threadIdx.x;
    float x0 = x[t], x1 = x[t + 256];
    float s = x0 + x1, sq = x0 * x0 + x1 * x1;
#pragma unroll
    for (int off = 32; off > 0; off >>= 1) {
        s += __shfl_xor(s, off, 64);
        sq += __shfl_xor(sq, off, 64);
    }
    __shared__ float rs[4], rq[4];
    int wave = t >> 6, lane = t & 63;
    if (lane == 0) { rs[wave] = s; rq[wave] = sq; }
    __syncthreads();
    s = rs[0] + rs[1] + rs[2] + rs[3];
    sq = rq[0] + rq[1] + rq[2] + rq[3];
    float mu = s * (1.f / 512.f);
    float var = sq * (1.f / 512.f) - mu * mu;
    float rstd = rsqrtf(var + 1e-5f);
    float y0 = (x0 - mu) * rstd * g[t] + bta[t];
    float y1 = (x1 - mu) * rstd * g[t + 256] + bta[t + 256];
    if (out_f32) {
        OutF[(long)row * 512 + t] = y0;
        OutF[(long)row * 512 + t + 256] = y1;
    } else {
        OutB[(long)row * 512 + t] = f2bf(y0);
        OutB[(long)row * 512 + t + 256] = f2bf(y1);
    }
}

// ---------------------------------------------------------------------------
extern "C" void kernel_launch(void* const* d_in, const int* in_sizes, int n_in,
                              void* d_out, int out_size, void* d_ws, size_t ws_size,
                              hipStream_t stream) {
    const float* q  = (const float*)d_in[0];
    const float* k  = (const float*)d_in[1];
    const float* v  = (const float*)d_in[2];
    const float* Wq = (const float*)d_in[3];
    const float* Wk = (const float*)d_in[4];
    const float* Wv = (const float*)d_in[5];
    const float* Wm = (const float*)d_in[6];
    const float* W1 = (const float*)d_in[7];
    const float* W2 = (const float*)d_in[8];
    const float* g1 = (const float*)d_in[9];
    const float* b1 = (const float*)d_in[10];
    const float* g2 = (const float*)d_in[11];
    const float* b2 = (const float*)d_in[12];

    char* ws = (char*)d_ws;
    // workspace layout (bytes); high-water ~124MB
    u16* WTq = (u16*)(ws + 0);            // 512KB each; WTq|WTk|WTv contiguous
    u16* WTk = (u16*)(ws + 524288);
    u16* WTv = (u16*)(ws + 1048576);
    u16* WTm = (u16*)(ws + 1572864);
    u16* W1T = (u16*)(ws + 2097152);      // [2048,512] 2MB
    u16* W2T = (u16*)(ws + 4194304);      // [512,2048] 2MB
    u16* qc  = (u16*)(ws + 6291456);      // bf16 casts, CONTIGUOUS 16.8MB each
    u16* kc  = (u16*)(ws + 23068672);
    u16* vc  = (u16*)(ws + 39845888);
    u16* Qb  = (u16*)(ws + 56623104);     // projections, CONTIGUOUS 16.8MB each
    u16* Kb  = (u16*)(ws + 73400320);
    u16* Vb  = (u16*)(ws + 90177536);
    float* KVb = (float*)(ws + 106954752); // 512KB
    float* KSb = (float*)(ws + 107479040); // 8KB
    u16* Msg = (u16*)(ws + 107487232);    // 16.8MB -> high-water 124264448
    float* Part = (float*)(ws + 23068672); // 16.8MB partial KV (kc/vc dead)
    float* KsPart = (float*)(ws + 6291456);// 256KB (qc dead after projections)
    float* xpre = (float*)(ws + 23068672); // 33.5MB (Part dead after reduce)
    u16* x1  = qc;                         // reuses qc (KsPart dead by LN1)
    u16* Hid = (u16*)(ws + 56623104);     // 67MB, reuses Qb..Msg (dead at FFN)

    // fp32 -> bf16 casts of activations
    f2b_k<<<dim3(8192), 256, 0, stream>>>(q, qc, 8388608);
    f2b_k<<<dim3(8192), 256, 0, stream>>>(k, kc, 8388608);
    f2b_k<<<dim3(8192), 256, 0, stream>>>(v, vc, 8388608);

    // weight transposes + cast ([in,out] fp32 -> [out,in] bf16)
    transpose_k<<<dim3(1024), 256, 0, stream>>>(Wq, WTq, 512, 512);
    transpose_k<<<dim3(1024), 256, 0, stream>>>(Wk, WTk, 512, 512);
    transpose_k<<<dim3(1024), 256, 0, stream>>>(Wv, WTv, 512, 512);
    transpose_k<<<dim3(1024), 256, 0, stream>>>(Wm, WTm, 512, 512);
    transpose_k<<<dim3(4096), 256, 0, stream>>>(W1, W1T, 512, 2048);
    transpose_k<<<dim3(4096), 256, 0, stream>>>(W2, W2T, 2048, 512);

    // batched q/k/v projections: one dispatch, N=1536 (A and C offset by
    // n0>>9 inside; elu1 fused for q,k; plain bf16 for v). 1536 blocks.
    gemm_bt<<<dim3(12, 128), 256, 0, stream>>>(qc, WTq, Qb, nullptr, 16384, 1536, 512, EPI_PROJ3);

    // linear attention: two-stage KV (no atomics), then msg
    kv_part<<<dim3(32, 32), 256, 0, stream>>>(Kb, Vb, Part, KsPart);
    kv_reduce<<<dim3(520), 256, 0, stream>>>(Part, KsPart, KVb, KSb);
    msg_k<<<dim3(32, 64), 256, 0, stream>>>(Qb, KVb, KSb, Msg);

    // merge + residual(q fp32) + LN1 (bf16 out for FFN input)
    gemm_bt<<<dim3(4, 128), 256, 0, stream>>>(Msg, WTm, xpre, q, 16384, 512, 512, EPI_ADDRES_F32);
    ln_k<<<dim3(16384), 256, 0, stream>>>(xpre, g1, b1, x1, nullptr, 0);

    // FFN + residual(q fp32) + LN2 (fp32 out -> d_out)
    gemm_bt<<<dim3(16, 128), 256, 0, stream>>>(x1, W1T, Hid, nullptr, 16384, 2048, 512, EPI_RELU);
    gemm_bt<<<dim3(4, 128), 256, 0, stream>>>(Hid, W2T, xpre, q, 16384, 512, 2048, EPI_ADDRES_F32);
    ln_k<<<dim3(16384), 256, 0, stream>>>(xpre, g2, b2, nullptr, (float*)d_out, 1);
}

// Round 9
// 476.817 us; speedup vs baseline: 1.2570x; 1.0687x over previous
//
#include <hip/hip_runtime.h>

typedef unsigned short u16;
typedef unsigned int u32;

typedef __bf16 bf16x8 __attribute__((ext_vector_type(8)));
typedef float f32x4 __attribute__((ext_vector_type(4)));

#define EPI_BF16 0
#define EPI_ELU1 1
#define EPI_RELU 2
#define EPI_ADDRES_F32 3
#define EPI_PROJ3 4

__device__ __forceinline__ float bf2f(u16 x) {
    u32 u = ((u32)x) << 16;
    return __uint_as_float(u);
}
__device__ __forceinline__ u16 f2bf(float f) {
    u32 u = __float_as_uint(f);
    u32 r = (u + 0x7FFFu + ((u >> 16) & 1u)) >> 16;
    return (u16)r;
}

// async global->LDS, 16B per lane; LDS dest = wave-uniform base + lane*16
__device__ __forceinline__ void gload_lds16(const u16* g, u16* l) {
    __builtin_amdgcn_global_load_lds(
        (const __attribute__((address_space(1))) u32*)g,
        (__attribute__((address_space(3))) u32*)l, 16, 0, 0);
}

// ---------------------------------------------------------------------------
// fp32 -> bf16 of q,k,v in ONE dispatch (dests qc|kc|vc contiguous).
// grid 24576: blocks [0,8192) q, [8192,16384) k, rest v. 4 elems/thread.
// ---------------------------------------------------------------------------
__global__ __launch_bounds__(256) void f2b3_k(
    const float* __restrict__ q, const float* __restrict__ k,
    const float* __restrict__ v, u16* __restrict__ out) {
    int bid = blockIdx.x;
    int w = bid >> 13;                       // 0,1,2
    const float* in = (w == 0) ? q : (w == 1) ? k : v;
    int i = ((bid & 8191) * 256 + threadIdx.x) * 4;
    float4 f = *(const float4*)(in + i);
    ushort4 o;
    o.x = f2bf(f.x); o.y = f2bf(f.y); o.z = f2bf(f.z); o.w = f2bf(f.w);
    *(ushort4*)(out + (long)w * 8388608 + i) = o;
}

// ---------------------------------------------------------------------------
// 4x 512x512 weight transpose+cast in one dispatch (dests WTq..WTm contiguous)
// ---------------------------------------------------------------------------
__global__ __launch_bounds__(256) void transpose4_k(
    const float* __restrict__ W0, const float* __restrict__ W1,
    const float* __restrict__ W2, const float* __restrict__ W3,
    u16* __restrict__ out) {
    int idx = blockIdx.x * 256 + threadIdx.x;        // 4*262144
    int w = idx >> 18, local = idx & 262143;
    const float* in = (w == 0) ? W0 : (w == 1) ? W1 : (w == 2) ? W2 : W3;
    int c = local >> 9, r = local & 511;             // out = c*512 + r
    out[idx] = f2bf(in[r * 512 + c]);
}

// ---------------------------------------------------------------------------
// W1 [512,2048] + W2 [2048,512] transpose+cast in one dispatch (dests contig)
// ---------------------------------------------------------------------------
__global__ __launch_bounds__(256) void transpose2_k(
    const float* __restrict__ W1, const float* __restrict__ W2,
    u16* __restrict__ out) {
    int idx = blockIdx.x * 256 + threadIdx.x;        // 2*1048576
    if (idx < 1048576) {
        int c = idx / 512, r = idx % 512;            // W1T[c*512+r]=W1[r*2048+c]
        out[idx] = f2bf(W1[(long)r * 2048 + c]);
    } else {
        int local = idx - 1048576;
        int c = local / 2048, r = local % 2048;      // W2T[c*2048+r]=W2[r*512+c]
        out[idx] = f2bf(W2[(long)r * 512 + c]);
    }
}

// ---------------------------------------------------------------------------
// GEMM BK=32: C[M,N] = A[M,K] @ Bt[N,K]^T, fp32 accum, fused epilogue.
// 128x128 tile, 4 waves (2x2 of 64x64), mfma_f32_16x16x32_bf16. r3 schedule
// (2-buf, issue-next-early, vmcnt(0)+__syncthreads — r4-r6 proved counted
// vmcnt/sched_barrier grafts REGRESS on this loop; r8 proved the read-XOR
// swizzle changes nothing). Plain r3 addressing. XCD-chunked block swizzle
// (FETCH 150->57.5MB). Used for large grids (PROJ3 1536 blocks, FFN1 2048
// blocks) where 32KB LDS preserves multi-block occupancy.
// ---------------------------------------------------------------------------
__global__ __launch_bounds__(256) void gemm_bt(
    const u16* __restrict__ A, const u16* __restrict__ Bt,
    void* __restrict__ C, const float* __restrict__ Res,
    int M, int N, int K, int epi)
{
    __shared__ __align__(16) u16 As[2][4096];
    __shared__ __align__(16) u16 Bs[2][4096];

    int t = threadIdx.x;
    int gx = gridDim.x;
    int nwg = gx * gridDim.y;
    int bid = blockIdx.y * gx + blockIdx.x;
    if ((nwg & 7) == 0) {
        int cpx = nwg >> 3;
        bid = (bid & 7) * cpx + (bid >> 3);
    }
    int m0 = (bid / gx) * 128, n0 = (bid % gx) * 128;

    int third = 0;
    if (epi == EPI_PROJ3) {
        third = n0 >> 9;                 // 0:q 1:k 2:v
        A += (long)third * 8388608;
    }

    int wave = t >> 6, lane = t & 63;
    int wm = (wave >> 1) * 64, wn = (wave & 1) * 64;
    int lrow = lane & 15, lk8 = (lane >> 4) * 8;

    f32x4 acc[4][4] = {};

    int srow = wave * 16 + (lane >> 2);
    int scol = (lane & 3) * 8;
    const u16* pA0 = A + (long)(m0 + srow) * K + scol;
    const u16* pB0 = Bt + (long)(n0 + srow) * K + scol;
    const long s64 = (long)64 * K;

    int nt = K >> 5;
    int cur = 0;

    {
        u16* a = As[0] + wave * 512;
        u16* b = Bs[0] + wave * 512;
        gload_lds16(pA0, a);
        gload_lds16(pA0 + s64, a + 2048);
        gload_lds16(pB0, b);
        gload_lds16(pB0 + s64, b + 2048);
    }
    __builtin_amdgcn_s_waitcnt(0);
    __syncthreads();

    for (int kt = 0; kt < nt; ++kt) {
        if (kt + 1 < nt) {
            int k0 = (kt + 1) << 5;
            u16* a = As[cur ^ 1] + wave * 512;
            u16* b = Bs[cur ^ 1] + wave * 512;
            gload_lds16(pA0 + k0, a);
            gload_lds16(pA0 + s64 + k0, a + 2048);
            gload_lds16(pB0 + k0, b);
            gload_lds16(pB0 + s64 + k0, b + 2048);
        }

        const u16* As_c = As[cur];
        const u16* Bs_c = Bs[cur];
        bf16x8 af[4], bfr[4];
#pragma unroll
        for (int mi = 0; mi < 4; mi++)
            af[mi] = *(const bf16x8*)(As_c + (wm + mi * 16 + lrow) * 32 + lk8);
#pragma unroll
        for (int ni = 0; ni < 4; ni++)
            bfr[ni] = *(const bf16x8*)(Bs_c + (wn + ni * 16 + lrow) * 32 + lk8);
#pragma unroll
        for (int mi = 0; mi < 4; mi++)
#pragma unroll
            for (int ni = 0; ni < 4; ni++)
                acc[mi][ni] = __builtin_amdgcn_mfma_f32_16x16x32_bf16(
                    af[mi], bfr[ni], acc[mi][ni], 0, 0, 0);

        if (kt + 1 < nt) {
            __builtin_amdgcn_s_waitcnt(0);
            __syncthreads();
            cur ^= 1;
        }
    }

    int rq = (lane >> 4) * 4;
    int colb = n0 + wn + (lane & 15);
#pragma unroll
    for (int mi = 0; mi < 4; mi++) {
#pragma unroll
        for (int ni = 0; ni < 4; ni++) {
#pragma unroll
            for (int r = 0; r < 4; r++) {
                int row = m0 + wm + mi * 16 + rq + r;
                int col = colb + ni * 16;
                float v0 = acc[mi][ni][r];
                if (epi == EPI_PROJ3) {
                    u16* Cb = (u16*)C + (long)third * 8388608;
                    long idx = (long)row * 512 + (col - (third << 9));
                    float v = (third < 2)
                                  ? (v0 > 0.f ? v0 + 1.f : __expf(v0))
                                  : v0;
                    Cb[idx] = f2bf(v);
                } else {
                    long idx = (long)row * N + col;
                    if (epi == EPI_ELU1) {
                        float v = v0 > 0.f ? v0 + 1.f : __expf(v0);
                        ((u16*)C)[idx] = f2bf(v);
                    } else if (epi == EPI_RELU) {
                        ((u16*)C)[idx] = f2bf(v0 > 0.f ? v0 : 0.f);
                    } else if (epi == EPI_ADDRES_F32) {
                        ((float*)C)[idx] = v0 + Res[idx];
                    } else {
                        ((u16*)C)[idx] = f2bf(v0);
                    }
                }
            }
        }
    }
}

// ---------------------------------------------------------------------------
// GEMM BK=64: same structure, one K-step = TWO r3-subtiles ([2][128][32]
// layout per buffer; staging/read addressing byte-identical per subtile) and
// 32 MFMAs per barrier. Halves the barrier/drain count — at 2 blocks/CU
// (512-block grids: merge GEMM, FFN2) the per-step drain is ~2500cyc exposed
// latency (r8: 76us/64 steps, MfmaUtil 17%), so fewer+fatter steps win. LDS
// 64KB -> still 2 blocks/CU, which these grids are grid-limited to anyway.
// NOT used for FFN1/PROJ3 (their 2048/1536-block grids need 32KB occupancy
// — the r4 lesson). k ascends (kk=0 then 1) -> bit-identical accumulation.
// ---------------------------------------------------------------------------
__global__ __launch_bounds__(256) void gemm_bt64(
    const u16* __restrict__ A, const u16* __restrict__ Bt,
    void* __restrict__ C, const float* __restrict__ Res,
    int M, int N, int K, int epi)
{
    __shared__ __align__(16) u16 As[2][8192];   // [buf][subtile kk][128*32]
    __shared__ __align__(16) u16 Bs[2][8192];

    int t = threadIdx.x;
    int gx = gridDim.x;
    int nwg = gx * gridDim.y;
    int bid = blockIdx.y * gx + blockIdx.x;
    if ((nwg & 7) == 0) {
        int cpx = nwg >> 3;
        bid = (bid & 7) * cpx + (bid >> 3);
    }
    int m0 = (bid / gx) * 128, n0 = (bid % gx) * 128;

    int wave = t >> 6, lane = t & 63;
    int wm = (wave >> 1) * 64, wn = (wave & 1) * 64;
    int lrow = lane & 15, lk8 = (lane >> 4) * 8;

    f32x4 acc[4][4] = {};

    int srow = wave * 16 + (lane >> 2);
    int scol = (lane & 3) * 8;
    const u16* pA0 = A + (long)(m0 + srow) * K + scol;
    const u16* pB0 = Bt + (long)(n0 + srow) * K + scol;
    const long s64 = (long)64 * K;

    int nt = K >> 6;
    int cur = 0;

    // prologue: stage tile 0 (both subtiles) into buffer 0
    {
        u16* a = As[0] + wave * 512;
        u16* b = Bs[0] + wave * 512;
#pragma unroll
        for (int kk = 0; kk < 2; kk++) {
            gload_lds16(pA0 + kk * 32, a + kk * 4096);
            gload_lds16(pA0 + s64 + kk * 32, a + kk * 4096 + 2048);
            gload_lds16(pB0 + kk * 32, b + kk * 4096);
            gload_lds16(pB0 + s64 + kk * 32, b + kk * 4096 + 2048);
        }
    }
    __builtin_amdgcn_s_waitcnt(0);
    __syncthreads();

    for (int kt = 0; kt < nt; ++kt) {
        if (kt + 1 < nt) {
            int k0 = (kt + 1) << 6;
            u16* a = As[cur ^ 1] + wave * 512;
            u16* b = Bs[cur ^ 1] + wave * 512;
#pragma unroll
            for (int kk = 0; kk < 2; kk++) {
                gload_lds16(pA0 + k0 + kk * 32, a + kk * 4096);
                gload_lds16(pA0 + s64 + k0 + kk * 32, a + kk * 4096 + 2048);
                gload_lds16(pB0 + k0 + kk * 32, b + kk * 4096);
                gload_lds16(pB0 + s64 + k0 + kk * 32, b + kk * 4096 + 2048);
            }
        }

#pragma unroll
        for (int kk = 0; kk < 2; kk++) {
            const u16* As_c = As[cur] + kk * 4096;
            const u16* Bs_c = Bs[cur] + kk * 4096;
            bf16x8 af[4], bfr[4];
#pragma unroll
            for (int mi = 0; mi < 4; mi++)
                af[mi] = *(const bf16x8*)(As_c + (wm + mi * 16 + lrow) * 32 + lk8);
#pragma unroll
            for (int ni = 0; ni < 4; ni++)
                bfr[ni] = *(const bf16x8*)(Bs_c + (wn + ni * 16 + lrow) * 32 + lk8);
#pragma unroll
            for (int mi = 0; mi < 4; mi++)
#pragma unroll
                for (int ni = 0; ni < 4; ni++)
                    acc[mi][ni] = __builtin_amdgcn_mfma_f32_16x16x32_bf16(
                        af[mi], bfr[ni], acc[mi][ni], 0, 0, 0);
        }

        if (kt + 1 < nt) {
            __builtin_amdgcn_s_waitcnt(0);
            __syncthreads();
            cur ^= 1;
        }
    }

    int rq = (lane >> 4) * 4;
    int colb = n0 + wn + (lane & 15);
#pragma unroll
    for (int mi = 0; mi < 4; mi++) {
#pragma unroll
        for (int ni = 0; ni < 4; ni++) {
#pragma unroll
            for (int r = 0; r < 4; r++) {
                int row = m0 + wm + mi * 16 + rq + r;
                int col = colb + ni * 16;
                long idx = (long)row * N + col;
                float v0 = acc[mi][ni][r];
                if (epi == EPI_ELU1) {
                    float v = v0 > 0.f ? v0 + 1.f : __expf(v0);
                    ((u16*)C)[idx] = f2bf(v);
                } else if (epi == EPI_RELU) {
                    ((u16*)C)[idx] = f2bf(v0 > 0.f ? v0 : 0.f);
                } else if (epi == EPI_ADDRES_F32) {
                    ((float*)C)[idx] = v0 + Res[idx];
                } else {
                    ((u16*)C)[idx] = f2bf(v0);
                }
            }
        }
    }
}

// ---------------------------------------------------------------------------
// KV stage 1: 32 splits x 128 s-rows (2 staged 64-row tiles per block);
// Part = 16.8MB. Ascending s order -> bit-identical KV. grid (32,32).
// ---------------------------------------------------------------------------
__global__ __launch_bounds__(256) void kv_part(
    const u16* __restrict__ Kf, const u16* __restrict__ Vf,
    float* __restrict__ Part, float* __restrict__ KsPart)
{
    __shared__ float sKf[64 * 68];
    __shared__ float sVf[64 * 68];
    int bh = blockIdx.x;
    int b = bh >> 3, h = bh & 7;
    int t = threadIdx.x;
    int d = t & 63, vg = t >> 6;

    float acc[16] = {};
    float ks = 0.f;

    for (int st = 0; st < 2; ++st) {
        int s0 = blockIdx.y * 128 + st * 64;
        {
            int row = t >> 2, c16 = (t & 3) * 16;
            long g = ((long)b * 4096 + s0 + row) * 512 + h * 64 + c16;
            uint4 kk0 = *(const uint4*)(Kf + g);
            uint4 kk1 = *(const uint4*)(Kf + g + 8);
            uint4 vv0 = *(const uint4*)(Vf + g);
            uint4 vv1 = *(const uint4*)(Vf + g + 8);
            float* dk = sKf + row * 68 + c16;
            float* dv = sVf + row * 68 + c16;
            u32 kw[8] = {kk0.x, kk0.y, kk0.z, kk0.w, kk1.x, kk1.y, kk1.z, kk1.w};
            u32 vw[8] = {vv0.x, vv0.y, vv0.z, vv0.w, vv1.x, vv1.y, vv1.z, vv1.w};
#pragma unroll
            for (int j = 0; j < 8; j++) {
                dk[2 * j]     = __uint_as_float(kw[j] << 16);
                dk[2 * j + 1] = __uint_as_float(kw[j] & 0xFFFF0000u);
                dv[2 * j]     = __uint_as_float(vw[j] << 16);
                dv[2 * j + 1] = __uint_as_float(vw[j] & 0xFFFF0000u);
            }
        }
        __syncthreads();

#pragma unroll 4
        for (int s = 0; s < 64; s++) {
            float kd = sKf[s * 68 + d];
            if (vg == 0) ks += kd;
            const float* vr = sVf + s * 68 + vg * 16;
            float4 v0 = *(const float4*)(vr);
            float4 v1 = *(const float4*)(vr + 4);
            float4 v2 = *(const float4*)(vr + 8);
            float4 v3 = *(const float4*)(vr + 12);
            acc[0]  += kd * v0.x; acc[1]  += kd * v0.y;
            acc[2]  += kd * v0.z; acc[3]  += kd * v0.w;
            acc[4]  += kd * v1.x; acc[5]  += kd * v1.y;
            acc[6]  += kd * v1.z; acc[7]  += kd * v1.w;
            acc[8]  += kd * v2.x; acc[9]  += kd * v2.y;
            acc[10] += kd * v2.z; acc[11] += kd * v2.w;
            acc[12] += kd * v3.x; acc[13] += kd * v3.y;
            acc[14] += kd * v3.z; acc[15] += kd * v3.w;
        }
        __syncthreads();
    }

    float* pp = Part + ((long)bh * 32 + blockIdx.y) * 4096 + d * 64 + vg * 16;
#pragma unroll
    for (int j = 0; j < 16; j++) pp[j] = acc[j];
    if (vg == 0) KsPart[((bh * 32) + blockIdx.y) * 64 + d] = ks;
}

// ---------------------------------------------------------------------------
// KV stage 2: KV[bh][dv] = sum over 32 splits; Ksum in tail blocks.
// ---------------------------------------------------------------------------
__global__ __launch_bounds__(256) void kv_reduce(
    const float* __restrict__ Part, const float* __restrict__ KsPart,
    float* __restrict__ KV, float* __restrict__ Ksum)
{
    int i = blockIdx.x * 256 + threadIdx.x;
    if (i < 131072) {
        int bh = i >> 12, dv = i & 4095;
        const float* p = Part + (long)bh * 32 * 4096 + dv;
        float s = 0.f;
#pragma unroll 8
        for (int sp = 0; sp < 32; sp++) s += p[(long)sp * 4096];
        KV[i] = s;
    } else if (i < 133120) {
        int j = i - 131072;
        int bh = j >> 6, d = j & 63;
        const float* p = KsPart + bh * 32 * 64 + d;
        float s = 0.f;
#pragma unroll 8
        for (int sp = 0; sp < 32; sp++) s += p[sp * 64];
        Ksum[j] = s;
    }
}

// ---------------------------------------------------------------------------
// msg[b,l,h,v] = (sum_d Q[b,l,h,d]*KV[bh][d][v]) / (Q . Ksum + eps)
// ---------------------------------------------------------------------------
__global__ __launch_bounds__(256) void msg_k(
    const u16* __restrict__ Q, const float* __restrict__ KV,
    const float* __restrict__ Ksum, u16* __restrict__ Msg)
{
    __shared__ float sKVt[64 * 68];
    __shared__ float sQ[64 * 68];
    __shared__ float sKs[64];
    __shared__ float sZ[64];

    int bh = blockIdx.x;
    int b = bh >> 3, h = bh & 7;
    int l0 = blockIdx.y * 64;
    int t = threadIdx.x, wave = t >> 6, lane = t & 63;

    {
        const float* src = KV + (long)bh * 4096 + t * 16;
        int d = t >> 2;
        int v0 = (t & 3) * 16;
        float4 a0 = *(const float4*)(src);
        float4 a1 = *(const float4*)(src + 4);
        float4 a2 = *(const float4*)(src + 8);
        float4 a3 = *(const float4*)(src + 12);
        float tmp[16] = {a0.x, a0.y, a0.z, a0.w, a1.x, a1.y, a1.z, a1.w,
                         a2.x, a2.y, a2.z, a2.w, a3.x, a3.y, a3.z, a3.w};
#pragma unroll
        for (int j = 0; j < 16; j++) sKVt[(v0 + j) * 68 + d] = tmp[j];
    }
    {
        int row = t >> 2, c = (t & 3) * 16;
        const u16* src = Q + ((long)b * 4096 + l0 + row) * 512 + h * 64 + c;
        uint4 q0 = *(const uint4*)(src);
        uint4 q1 = *(const uint4*)(src + 8);
        float* dq = sQ + row * 68 + c;
        u32 qw[8] = {q0.x, q0.y, q0.z, q0.w, q1.x, q1.y, q1.z, q1.w};
#pragma unroll
        for (int j = 0; j < 8; j++) {
            dq[2 * j]     = __uint_as_float(qw[j] << 16);
            dq[2 * j + 1] = __uint_as_float(qw[j] & 0xFFFF0000u);
        }
    }
    if (t < 64) sKs[t] = Ksum[bh * 64 + t];
    __syncthreads();

    float kv[64];
    {
        const float* kr = sKVt + lane * 68;
#pragma unroll
        for (int j = 0; j < 16; j++) {
            float4 x = *(const float4*)(kr + 4 * j);
            kv[4 * j]     = x.x; kv[4 * j + 1] = x.y;
            kv[4 * j + 2] = x.z; kv[4 * j + 3] = x.w;
        }
    }
    if (t < 64) {
        const float* qr = sQ + t * 68;
        float zp = 0.f;
#pragma unroll
        for (int d = 0; d < 64; d++) zp += qr[d] * sKs[d];
        sZ[t] = 1.f / (zp + 1e-6f);
    }
    __syncthreads();

    const long obase = ((long)b * 4096 + l0) * 512 + h * 64 + lane;
    int lbase = wave * 16;
#pragma unroll 4
    for (int i = 0; i < 16; i++) {
        int ll = lbase + i;
        const float* qr = sQ + ll * 68;
        float a0 = 0.f, a1 = 0.f, a2 = 0.f, a3 = 0.f;
#pragma unroll
        for (int db = 0; db < 16; db++) {
            float4 q4 = *(const float4*)(qr + 4 * db);
            a0 += q4.x * kv[4 * db];
            a1 += q4.y * kv[4 * db + 1];
            a2 += q4.z * kv[4 * db + 2];
            a3 += q4.w * kv[4 * db + 3];
        }
        float acc = (a0 + a1) + (a2 + a3);
        Msg[obase + (long)ll * 512] = f2bf(acc * sZ[ll]);
    }
}

// ---------------------------------------------------------------------------
// LayerNorm over 512 cols, fp32 input, fp32 gamma/beta.
// ---------------------------------------------------------------------------
__global__ __launch_bounds__(256) void ln_k(
    const float* __restrict__ X, const float* __restrict__ g,
    const float* __restrict__ bta, u16* __restrict__ OutB,
    float* __restrict__ OutF, int out_f32)
{
    int row = blockIdx.x;
    const float* x = X + (long)row * 512;
    int t = threadIdx.x;
    float x0 = x[t], x1 = x[t + 256];
    float s = x0 + x1, sq = x0 * x0 + x1 * x1;
#pragma unroll
    for (int off = 32; off > 0; off >>= 1) {
        s += __shfl_xor(s, off, 64);
        sq += __shfl_xor(sq, off, 64);
    }
    __shared__ float rs[4], rq[4];
    int wave = t >> 6, lane = t & 63;
    if (lane == 0) { rs[wave] = s; rq[wave] = sq; }
    __syncthreads();
    s = rs[0] + rs[1] + rs[2] + rs[3];
    sq = rq[0] + rq[1] + rq[2] + rq[3];
    float mu = s * (1.f / 512.f);
    float var = sq * (1.f / 512.f) - mu * mu;
    float rstd = rsqrtf(var + 1e-5f);
    float y0 = (x0 - mu) * rstd * g[t] + bta[t];
    float y1 = (x1 - mu) * rstd * g[t + 256] + bta[t + 256];
    if (out_f32) {
        OutF[(long)row * 512 + t] = y0;
        OutF[(long)row * 512 + t + 256] = y1;
    } else {
        OutB[(long)row * 512 + t] = f2bf(y0);
        OutB[(long)row * 512 + t + 256] = f2bf(y1);
    }
}

// ---------------------------------------------------------------------------
extern "C" void kernel_launch(void* const* d_in, const int* in_sizes, int n_in,
                              void* d_out, int out_size, void* d_ws, size_t ws_size,
                              hipStream_t stream) {
    const float* q  = (const float*)d_in[0];
    const float* k  = (const float*)d_in[1];
    const float* v  = (const float*)d_in[2];
    const float* Wq = (const float*)d_in[3];
    const float* Wk = (const float*)d_in[4];
    const float* Wv = (const float*)d_in[5];
    const float* Wm = (const float*)d_in[6];
    const float* W1 = (const float*)d_in[7];
    const float* W2 = (const float*)d_in[8];
    const float* g1 = (const float*)d_in[9];
    const float* b1 = (const float*)d_in[10];
    const float* g2 = (const float*)d_in[11];
    const float* b2 = (const float*)d_in[12];

    char* ws = (char*)d_ws;
    // workspace layout (bytes); high-water ~124MB
    u16* WTq = (u16*)(ws + 0);            // 512KB each; WTq..WTm contiguous
    u16* W1T = (u16*)(ws + 2097152);      // [2048,512] 2MB; W1T|W2T contiguous
    u16* qc  = (u16*)(ws + 6291456);      // bf16 casts, CONTIGUOUS 16.8MB each
    u16* Qb  = (u16*)(ws + 56623104);     // projections, CONTIGUOUS 16.8MB each
    u16* Kb  = (u16*)(ws + 73400320);
    u16* Vb  = (u16*)(ws + 90177536);
    float* KVb = (float*)(ws + 106954752); // 512KB
    float* KSb = (float*)(ws + 107479040); // 8KB
    u16* Msg = (u16*)(ws + 107487232);    // 16.8MB -> high-water 124264448
    float* Part = (float*)(ws + 23068672); // 16.8MB partial KV (kc/vc dead)
    float* KsPart = (float*)(ws + 6291456);// 256KB (qc dead after projections)
    float* xpre = (float*)(ws + 23068672); // 33.5MB (Part dead after reduce)
    u16* x1  = qc;                         // reuses qc (KsPart dead by LN1)
    u16* Hid = (u16*)(ws + 56623104);     // 67MB, reuses Qb..Msg (dead at FFN)

    // fp32 -> bf16 casts of q,k,v (one dispatch)
    f2b3_k<<<dim3(24576), 256, 0, stream>>>(q, k, v, qc);

    // weight transposes + cast (two dispatches)
    transpose4_k<<<dim3(4096), 256, 0, stream>>>(Wq, Wk, Wv, Wm, WTq);
    transpose2_k<<<dim3(8192), 256, 0, stream>>>(W1, W2, W1T);

    // batched q/k/v projections: one dispatch, N=1536 (BK=32; 1536 blocks)
    gemm_bt<<<dim3(12, 128), 256, 0, stream>>>(qc, WTq, Qb, nullptr, 16384, 1536, 512, EPI_PROJ3);

    // linear attention: two-stage KV (no atomics), then msg
    kv_part<<<dim3(32, 32), 256, 0, stream>>>(Kb, Vb, Part, KsPart);
    kv_reduce<<<dim3(520), 256, 0, stream>>>(Part, KsPart, KVb, KSb);
    msg_k<<<dim3(32, 64), 256, 0, stream>>>(Qb, KVb, KSb, Msg);

    // merge + residual(q fp32) + LN1 (BK=64: 512-block grid, latency-bound)
    gemm_bt64<<<dim3(4, 128), 256, 0, stream>>>(Msg, (u16*)(ws + 1572864), xpre, q, 16384, 512, 512, EPI_ADDRES_F32);
    ln_k<<<dim3(16384), 256, 0, stream>>>(xpre, g1, b1, x1, nullptr, 0);

    // FFN1 (BK=32: 2048 blocks need 32KB-LDS occupancy)
    gemm_bt<<<dim3(16, 128), 256, 0, stream>>>(x1, W1T, Hid, nullptr, 16384, 2048, 512, EPI_RELU);
    // FFN2 (BK=64: 512-block grid, K=2048 — steps 64 -> 32)
    gemm_bt64<<<dim3(4, 128), 256, 0, stream>>>(Hid, (u16*)(ws + 4194304), xpre, q, 16384, 512, 2048, EPI_ADDRES_F32);
    ln_k<<<dim3(16384), 256, 0, stream>>>(xpre, g2, b2, nullptr, (float*)d_out, 1);
}

// Round 10
// 443.160 us; speedup vs baseline: 1.3525x; 1.0759x over previous
//
#include <hip/hip_runtime.h>

typedef unsigned short u16;
typedef unsigned int u32;

typedef __bf16 bf16x8 __attribute__((ext_vector_type(8)));
typedef float f32x4 __attribute__((ext_vector_type(4)));

#define EPI_BF16 0
#define EPI_ELU1 1
#define EPI_RELU 2
#define EPI_ADDRES_F32 3
#define EPI_PROJ3 4

__device__ __forceinline__ float bf2f(u16 x) {
    u32 u = ((u32)x) << 16;
    return __uint_as_float(u);
}
__device__ __forceinline__ u16 f2bf(float f) {
    u32 u = __float_as_uint(f);
    u32 r = (u + 0x7FFFu + ((u >> 16) & 1u)) >> 16;
    return (u16)r;
}

// async global->LDS, 16B per lane; LDS dest = wave-uniform base + lane*16
__device__ __forceinline__ void gload_lds16(const u16* g, u16* l) {
    __builtin_amdgcn_global_load_lds(
        (const __attribute__((address_space(1))) u32*)g,
        (__attribute__((address_space(3))) u32*)l, 16, 0, 0);
}

// ---------------------------------------------------------------------------
// Fused prep: fp32->bf16 of q,k,v + all weight transposes, ONE dispatch.
// blocks [0,24576): qkv cast; [24576,28672): Wq..Wm 512x512 transposes;
// [28672,36864): W1/W2 transposes. Disjoint outputs, no interaction.
// ---------------------------------------------------------------------------
__global__ __launch_bounds__(256) void prep_k(
    const float* __restrict__ q, const float* __restrict__ k,
    const float* __restrict__ v,
    const float* __restrict__ Wq, const float* __restrict__ Wk,
    const float* __restrict__ Wv, const float* __restrict__ Wm,
    const float* __restrict__ W1, const float* __restrict__ W2,
    u16* __restrict__ qkv_out, u16* __restrict__ wt4_out,
    u16* __restrict__ wt2_out)
{
    int bid = blockIdx.x;
    if (bid < 24576) {
        int w = bid >> 13;                       // 0:q 1:k 2:v
        const float* in = (w == 0) ? q : (w == 1) ? k : v;
        int i = ((bid & 8191) * 256 + threadIdx.x) * 4;
        float4 f = *(const float4*)(in + i);
        ushort4 o;
        o.x = f2bf(f.x); o.y = f2bf(f.y); o.z = f2bf(f.z); o.w = f2bf(f.w);
        *(ushort4*)(qkv_out + (long)w * 8388608 + i) = o;
    } else if (bid < 28672) {
        int idx = (bid - 24576) * 256 + threadIdx.x;     // 4*262144
        int w = idx >> 18, local = idx & 262143;
        const float* in = (w == 0) ? Wq : (w == 1) ? Wk : (w == 2) ? Wv : Wm;
        int c = local >> 9, r = local & 511;
        wt4_out[idx] = f2bf(in[r * 512 + c]);
    } else {
        int idx = (bid - 28672) * 256 + threadIdx.x;     // 2*1048576
        if (idx < 1048576) {
            int c = idx / 512, r = idx % 512;
            wt2_out[idx] = f2bf(W1[(long)r * 2048 + c]);
        } else {
            int local = idx - 1048576;
            int c = local / 2048, r = local % 2048;
            wt2_out[idx] = f2bf(W2[(long)r * 512 + c]);
        }
    }
}

// ---------------------------------------------------------------------------
// GEMM BK=32: C[M,N] = A[M,K] @ Bt[N,K]^T, fp32 accum, fused epilogue.
// 128x128 tile, 4 waves (2x2 of 64x64), mfma_f32_16x16x32_bf16. r3 schedule
// (2-buf, issue-next-early, vmcnt(0)+__syncthreads). XCD-chunked swizzle.
// Used for PROJ3 (1536 blocks).
// ---------------------------------------------------------------------------
__global__ __launch_bounds__(256) void gemm_bt(
    const u16* __restrict__ A, const u16* __restrict__ Bt,
    void* __restrict__ C, const float* __restrict__ Res,
    int M, int N, int K, int epi)
{
    __shared__ __align__(16) u16 As[2][4096];
    __shared__ __align__(16) u16 Bs[2][4096];

    int t = threadIdx.x;
    int gx = gridDim.x;
    int nwg = gx * gridDim.y;
    int bid = blockIdx.y * gx + blockIdx.x;
    if ((nwg & 7) == 0) {
        int cpx = nwg >> 3;
        bid = (bid & 7) * cpx + (bid >> 3);
    }
    int m0 = (bid / gx) * 128, n0 = (bid % gx) * 128;

    int third = 0;
    if (epi == EPI_PROJ3) {
        third = n0 >> 9;                 // 0:q 1:k 2:v
        A += (long)third * 8388608;
    }

    int wave = t >> 6, lane = t & 63;
    int wm = (wave >> 1) * 64, wn = (wave & 1) * 64;
    int lrow = lane & 15, lk8 = (lane >> 4) * 8;

    f32x4 acc[4][4] = {};

    int srow = wave * 16 + (lane >> 2);
    int scol = (lane & 3) * 8;
    const u16* pA0 = A + (long)(m0 + srow) * K + scol;
    const u16* pB0 = Bt + (long)(n0 + srow) * K + scol;
    const long s64 = (long)64 * K;

    int nt = K >> 5;
    int cur = 0;

    {
        u16* a = As[0] + wave * 512;
        u16* b = Bs[0] + wave * 512;
        gload_lds16(pA0, a);
        gload_lds16(pA0 + s64, a + 2048);
        gload_lds16(pB0, b);
        gload_lds16(pB0 + s64, b + 2048);
    }
    __builtin_amdgcn_s_waitcnt(0);
    __syncthreads();

    for (int kt = 0; kt < nt; ++kt) {
        if (kt + 1 < nt) {
            int k0 = (kt + 1) << 5;
            u16* a = As[cur ^ 1] + wave * 512;
            u16* b = Bs[cur ^ 1] + wave * 512;
            gload_lds16(pA0 + k0, a);
            gload_lds16(pA0 + s64 + k0, a + 2048);
            gload_lds16(pB0 + k0, b);
            gload_lds16(pB0 + s64 + k0, b + 2048);
        }

        const u16* As_c = As[cur];
        const u16* Bs_c = Bs[cur];
        bf16x8 af[4], bfr[4];
#pragma unroll
        for (int mi = 0; mi < 4; mi++)
            af[mi] = *(const bf16x8*)(As_c + (wm + mi * 16 + lrow) * 32 + lk8);
#pragma unroll
        for (int ni = 0; ni < 4; ni++)
            bfr[ni] = *(const bf16x8*)(Bs_c + (wn + ni * 16 + lrow) * 32 + lk8);
#pragma unroll
        for (int mi = 0; mi < 4; mi++)
#pragma unroll
            for (int ni = 0; ni < 4; ni++)
                acc[mi][ni] = __builtin_amdgcn_mfma_f32_16x16x32_bf16(
                    af[mi], bfr[ni], acc[mi][ni], 0, 0, 0);

        if (kt + 1 < nt) {
            __builtin_amdgcn_s_waitcnt(0);
            __syncthreads();
            cur ^= 1;
        }
    }

    int rq = (lane >> 4) * 4;
    int colb = n0 + wn + (lane & 15);
#pragma unroll
    for (int mi = 0; mi < 4; mi++) {
#pragma unroll
        for (int ni = 0; ni < 4; ni++) {
#pragma unroll
            for (int r = 0; r < 4; r++) {
                int row = m0 + wm + mi * 16 + rq + r;
                int col = colb + ni * 16;
                float v0 = acc[mi][ni][r];
                if (epi == EPI_PROJ3) {
                    u16* Cb = (u16*)C + (long)third * 8388608;
                    long idx = (long)row * 512 + (col - (third << 9));
                    float v = (third < 2)
                                  ? (v0 > 0.f ? v0 + 1.f : __expf(v0))
                                  : v0;
                    Cb[idx] = f2bf(v);
                } else {
                    long idx = (long)row * N + col;
                    if (epi == EPI_ELU1) {
                        float v = v0 > 0.f ? v0 + 1.f : __expf(v0);
                        ((u16*)C)[idx] = f2bf(v);
                    } else if (epi == EPI_RELU) {
                        ((u16*)C)[idx] = f2bf(v0 > 0.f ? v0 : 0.f);
                    } else if (epi == EPI_ADDRES_F32) {
                        ((float*)C)[idx] = v0 + Res[idx];
                    } else {
                        ((u16*)C)[idx] = f2bf(v0);
                    }
                }
            }
        }
    }
}

// ---------------------------------------------------------------------------
// GEMM BK=64: 32 MFMAs per barrier, half the drain count. r9 verified
// (FFN2/merge). Now ALSO used for FFN1: barriers/residency = 16/2.7 (BK32,
// measured occ 27%) vs 8/2 (BK64) -> BK64 wins; r4's contrary datapoint was
// poisoned by counted-vmcnt+sched_barrier, since reverted.
// ---------------------------------------------------------------------------
__global__ __launch_bounds__(256) void gemm_bt64(
    const u16* __restrict__ A, const u16* __restrict__ Bt,
    void* __restrict__ C, const float* __restrict__ Res,
    int M, int N, int K, int epi)
{
    __shared__ __align__(16) u16 As[2][8192];   // [buf][subtile kk][128*32]
    __shared__ __align__(16) u16 Bs[2][8192];

    int t = threadIdx.x;
    int gx = gridDim.x;
    int nwg = gx * gridDim.y;
    int bid = blockIdx.y * gx + blockIdx.x;
    if ((nwg & 7) == 0) {
        int cpx = nwg >> 3;
        bid = (bid & 7) * cpx + (bid >> 3);
    }
    int m0 = (bid / gx) * 128, n0 = (bid % gx) * 128;

    int wave = t >> 6, lane = t & 63;
    int wm = (wave >> 1) * 64, wn = (wave & 1) * 64;
    int lrow = lane & 15, lk8 = (lane >> 4) * 8;

    f32x4 acc[4][4] = {};

    int srow = wave * 16 + (lane >> 2);
    int scol = (lane & 3) * 8;
    const u16* pA0 = A + (long)(m0 + srow) * K + scol;
    const u16* pB0 = Bt + (long)(n0 + srow) * K + scol;
    const long s64 = (long)64 * K;

    int nt = K >> 6;
    int cur = 0;

    {
        u16* a = As[0] + wave * 512;
        u16* b = Bs[0] + wave * 512;
#pragma unroll
        for (int kk = 0; kk < 2; kk++) {
            gload_lds16(pA0 + kk * 32, a + kk * 4096);
            gload_lds16(pA0 + s64 + kk * 32, a + kk * 4096 + 2048);
            gload_lds16(pB0 + kk * 32, b + kk * 4096);
            gload_lds16(pB0 + s64 + kk * 32, b + kk * 4096 + 2048);
        }
    }
    __builtin_amdgcn_s_waitcnt(0);
    __syncthreads();

    for (int kt = 0; kt < nt; ++kt) {
        if (kt + 1 < nt) {
            int k0 = (kt + 1) << 6;
            u16* a = As[cur ^ 1] + wave * 512;
            u16* b = Bs[cur ^ 1] + wave * 512;
#pragma unroll
            for (int kk = 0; kk < 2; kk++) {
                gload_lds16(pA0 + k0 + kk * 32, a + kk * 4096);
                gload_lds16(pA0 + s64 + k0 + kk * 32, a + kk * 4096 + 2048);
                gload_lds16(pB0 + k0 + kk * 32, b + kk * 4096);
                gload_lds16(pB0 + s64 + k0 + kk * 32, b + kk * 4096 + 2048);
            }
        }

#pragma unroll
        for (int kk = 0; kk < 2; kk++) {
            const u16* As_c = As[cur] + kk * 4096;
            const u16* Bs_c = Bs[cur] + kk * 4096;
            bf16x8 af[4], bfr[4];
#pragma unroll
            for (int mi = 0; mi < 4; mi++)
                af[mi] = *(const bf16x8*)(As_c + (wm + mi * 16 + lrow) * 32 + lk8);
#pragma unroll
            for (int ni = 0; ni < 4; ni++)
                bfr[ni] = *(const bf16x8*)(Bs_c + (wn + ni * 16 + lrow) * 32 + lk8);
#pragma unroll
            for (int mi = 0; mi < 4; mi++)
#pragma unroll
                for (int ni = 0; ni < 4; ni++)
                    acc[mi][ni] = __builtin_amdgcn_mfma_f32_16x16x32_bf16(
                        af[mi], bfr[ni], acc[mi][ni], 0, 0, 0);
        }

        if (kt + 1 < nt) {
            __builtin_amdgcn_s_waitcnt(0);
            __syncthreads();
            cur ^= 1;
        }
    }

    int rq = (lane >> 4) * 4;
    int colb = n0 + wn + (lane & 15);
#pragma unroll
    for (int mi = 0; mi < 4; mi++) {
#pragma unroll
        for (int ni = 0; ni < 4; ni++) {
#pragma unroll
            for (int r = 0; r < 4; r++) {
                int row = m0 + wm + mi * 16 + rq + r;
                int col = colb + ni * 16;
                long idx = (long)row * N + col;
                float v0 = acc[mi][ni][r];
                if (epi == EPI_ELU1) {
                    float v = v0 > 0.f ? v0 + 1.f : __expf(v0);
                    ((u16*)C)[idx] = f2bf(v);
                } else if (epi == EPI_RELU) {
                    ((u16*)C)[idx] = f2bf(v0 > 0.f ? v0 : 0.f);
                } else if (epi == EPI_ADDRES_F32) {
                    ((float*)C)[idx] = v0 + Res[idx];
                } else {
                    ((u16*)C)[idx] = f2bf(v0);
                }
            }
        }
    }
}

// ---------------------------------------------------------------------------
// KV stage 1, MFMA version (Guideline 10: K=4096 contraction on matrix cores,
// not 16 VALU FMAs/lane/s). Per (bh, split of 128 s): stage K,V 64x64 tiles
// TRANSPOSED in LDS (sKt[d][s], sVt[v][s], bf16, row pad 72 u16 = 144B:
// 16B-aligned rows, 2-way-free b128 frag reads). Then
// mfma(Kt-frag, Vt-frag) = sum_s K[s,d]V[s,v] — same operand convention as
// gemm_bt (both frags k-contiguous; D[d-tile][v-tile]). 4 waves = 2x2 of
// 32x32 output quadrants, acc[2][2] f32x4. Ks[d] summed from sKt rows.
// grid (32,32). Numerics: same bf16*bf16+fp32, MFMA accumulation order.
// ---------------------------------------------------------------------------
__global__ __launch_bounds__(256) void kv_part(
    const u16* __restrict__ Kf, const u16* __restrict__ Vf,
    float* __restrict__ Part, float* __restrict__ KsPart)
{
    __shared__ __align__(16) u16 sKt[64 * 72];   // [d][s]
    __shared__ __align__(16) u16 sVt[64 * 72];   // [v][s]
    int bh = blockIdx.x;
    int b = bh >> 3, h = bh & 7;
    int t = threadIdx.x;
    int wave = t >> 6, lane = t & 63;
    int dblk = (wave >> 1) * 32, vblk = (wave & 1) * 32;
    int lrow = lane & 15, lk8 = (lane >> 4) * 8;

    f32x4 acc[2][2] = {};
    float ks = 0.f;

    int srow = t >> 2, c16 = (t & 3) * 16;

    for (int st = 0; st < 2; ++st) {
        int s0 = blockIdx.y * 128 + st * 64;
        {   // read K/V row srow (16 d-cols, coalesced), write LDS transposed
            long g = ((long)b * 4096 + s0 + srow) * 512 + h * 64 + c16;
            uint4 k0 = *(const uint4*)(Kf + g);
            uint4 k1 = *(const uint4*)(Kf + g + 8);
            uint4 v0 = *(const uint4*)(Vf + g);
            uint4 v1 = *(const uint4*)(Vf + g + 8);
            u32 kw[8] = {k0.x, k0.y, k0.z, k0.w, k1.x, k1.y, k1.z, k1.w};
            u32 vw[8] = {v0.x, v0.y, v0.z, v0.w, v1.x, v1.y, v1.z, v1.w};
            if (st) __syncthreads();   // WAR: prev iter's readers done
#pragma unroll
            for (int j = 0; j < 16; j++) {
                u16 kv_ = (u16)(kw[j >> 1] >> ((j & 1) * 16));
                u16 vv_ = (u16)(vw[j >> 1] >> ((j & 1) * 16));
                sKt[(c16 + j) * 72 + srow] = kv_;
                sVt[(c16 + j) * 72 + srow] = vv_;
            }
        }
        __syncthreads();

#pragma unroll
        for (int ksb = 0; ksb < 2; ++ksb) {
            int ko = ksb * 32 + lk8;
            bf16x8 a0 = *(const bf16x8*)(sKt + (dblk + lrow) * 72 + ko);
            bf16x8 a1 = *(const bf16x8*)(sKt + (dblk + 16 + lrow) * 72 + ko);
            bf16x8 b0 = *(const bf16x8*)(sVt + (vblk + lrow) * 72 + ko);
            bf16x8 b1 = *(const bf16x8*)(sVt + (vblk + 16 + lrow) * 72 + ko);
            acc[0][0] = __builtin_amdgcn_mfma_f32_16x16x32_bf16(a0, b0, acc[0][0], 0, 0, 0);
            acc[0][1] = __builtin_amdgcn_mfma_f32_16x16x32_bf16(a0, b1, acc[0][1], 0, 0, 0);
            acc[1][0] = __builtin_amdgcn_mfma_f32_16x16x32_bf16(a1, b0, acc[1][0], 0, 0, 0);
            acc[1][1] = __builtin_amdgcn_mfma_f32_16x16x32_bf16(a1, b1, acc[1][1], 0, 0, 0);
        }

        // Ks partial: thread d<64 sums its sKt row (64 s values)
        if (t < 64) {
            const u32* rowp = (const u32*)(sKt + t * 72);
#pragma unroll
            for (int c = 0; c < 32; c++) {
                u32 w = rowp[c];
                ks += bf2f((u16)w) + bf2f((u16)(w >> 16));
            }
        }
    }

    // epilogue: D[row=(lane>>4)*4+r][col=lane&15] per 16x16 tile
    int rq = (lane >> 4) * 4;
    float* pp = Part + ((long)bh * 32 + blockIdx.y) * 4096;
#pragma unroll
    for (int ti = 0; ti < 2; ti++)
#pragma unroll
        for (int tj = 0; tj < 2; tj++)
#pragma unroll
            for (int r = 0; r < 4; r++) {
                int d = dblk + ti * 16 + rq + r;
                int vcol = vblk + tj * 16 + (lane & 15);
                pp[d * 64 + vcol] = acc[ti][tj][r];
            }
    if (t < 64) KsPart[((bh * 32) + blockIdx.y) * 64 + t] = ks;
}

// ---------------------------------------------------------------------------
// KV stage 2: KV[bh][dv] = sum over 32 splits; Ksum in tail blocks.
// ---------------------------------------------------------------------------
__global__ __launch_bounds__(256) void kv_reduce(
    const float* __restrict__ Part, const float* __restrict__ KsPart,
    float* __restrict__ KV, float* __restrict__ Ksum)
{
    int i = blockIdx.x * 256 + threadIdx.x;
    if (i < 131072) {
        int bh = i >> 12, dv = i & 4095;
        const float* p = Part + (long)bh * 32 * 4096 + dv;
        float s = 0.f;
#pragma unroll 8
        for (int sp = 0; sp < 32; sp++) s += p[(long)sp * 4096];
        KV[i] = s;
    } else if (i < 133120) {
        int j = i - 131072;
        int bh = j >> 6, d = j & 63;
        const float* p = KsPart + bh * 32 * 64 + d;
        float s = 0.f;
#pragma unroll 8
        for (int sp = 0; sp < 32; sp++) s += p[sp * 64];
        Ksum[j] = s;
    }
}

// ---------------------------------------------------------------------------
// msg[b,l,h,v] = (sum_d Q[b,l,h,d]*KV[bh][d][v]) / (Q . Ksum + eps)
// ---------------------------------------------------------------------------
__global__ __launch_bounds__(256) void msg_k(
    const u16* __restrict__ Q, const float* __restrict__ KV,
    const float* __restrict__ Ksum, u16* __restrict__ Msg)
{
    __shared__ float sKVt[64 * 68];
    __shared__ float sQ[64 * 68];
    __shared__ float sKs[64];
    __shared__ float sZ[64];

    int bh = blockIdx.x;
    int b = bh >> 3, h = bh & 7;
    int l0 = blockIdx.y * 64;
    int t = threadIdx.x, wave = t >> 6, lane = t & 63;

    {
        const float* src = KV + (long)bh * 4096 + t * 16;
        int d = t >> 2;
        int v0 = (t & 3) * 16;
        float4 a0 = *(const float4*)(src);
        float4 a1 = *(const float4*)(src + 4);
        float4 a2 = *(const float4*)(src + 8);
        float4 a3 = *(const float4*)(src + 12);
        float tmp[16] = {a0.x, a0.y, a0.z, a0.w, a1.x, a1.y, a1.z, a1.w,
                         a2.x, a2.y, a2.z, a2.w, a3.x, a3.y, a3.z, a3.w};
#pragma unroll
        for (int j = 0; j < 16; j++) sKVt[(v0 + j) * 68 + d] = tmp[j];
    }
    {
        int row = t >> 2, c = (t & 3) * 16;
        const u16* src = Q + ((long)b * 4096 + l0 + row) * 512 + h * 64 + c;
        uint4 q0 = *(const uint4*)(src);
        uint4 q1 = *(const uint4*)(src + 8);
        float* dq = sQ + row * 68 + c;
        u32 qw[8] = {q0.x, q0.y, q0.z, q0.w, q1.x, q1.y, q1.z, q1.w};
#pragma unroll
        for (int j = 0; j < 8; j++) {
            dq[2 * j]     = __uint_as_float(qw[j] << 16);
            dq[2 * j + 1] = __uint_as_float(qw[j] & 0xFFFF0000u);
        }
    }
    if (t < 64) sKs[t] = Ksum[bh * 64 + t];
    __syncthreads();

    float kv[64];
    {
        const float* kr = sKVt + lane * 68;
#pragma unroll
        for (int j = 0; j < 16; j++) {
            float4 x = *(const float4*)(kr + 4 * j);
            kv[4 * j]     = x.x; kv[4 * j + 1] = x.y;
            kv[4 * j + 2] = x.z; kv[4 * j + 3] = x.w;
        }
    }
    if (t < 64) {
        const float* qr = sQ + t * 68;
        float zp = 0.f;
#pragma unroll
        for (int d = 0; d < 64; d++) zp += qr[d] * sKs[d];
        sZ[t] = 1.f / (zp + 1e-6f);
    }
    __syncthreads();

    const long obase = ((long)b * 4096 + l0) * 512 + h * 64 + lane;
    int lbase = wave * 16;
#pragma unroll 4
    for (int i = 0; i < 16; i++) {
        int ll = lbase + i;
        const float* qr = sQ + ll * 68;
        float a0 = 0.f, a1 = 0.f, a2 = 0.f, a3 = 0.f;
#pragma unroll
        for (int db = 0; db < 16; db++) {
            float4 q4 = *(const float4*)(qr + 4 * db);
            a0 += q4.x * kv[4 * db];
            a1 += q4.y * kv[4 * db + 1];
            a2 += q4.z * kv[4 * db + 2];
            a3 += q4.w * kv[4 * db + 3];
        }
        float acc = (a0 + a1) + (a2 + a3);
        Msg[obase + (long)ll * 512] = f2bf(acc * sZ[ll]);
    }
}

// ---------------------------------------------------------------------------
// LayerNorm, wave-per-row: lane holds 8 consecutive cols (32B coalesced);
// shuffle-only reduce (no LDS, no cross-wave sync); packed 16B bf16 store.
// 4 rows/block, grid 4096.
// ---------------------------------------------------------------------------
__global__ __launch_bounds__(256) void ln_k(
    const float* __restrict__ X, const float* __restrict__ g,
    const float* __restrict__ bta, u16* __restrict__ OutB,
    float* __restrict__ OutF, int out_f32)
{
    int wave = threadIdx.x >> 6, lane = threadIdx.x & 63;
    long row = (long)blockIdx.x * 4 + wave;
    const float* x = X + row * 512 + lane * 8;
    float4 a = *(const float4*)(x);
    float4 c = *(const float4*)(x + 4);
    float s = (a.x + a.y) + (a.z + a.w) + (c.x + c.y) + (c.z + c.w);
    float sq = a.x * a.x + a.y * a.y + a.z * a.z + a.w * a.w +
               c.x * c.x + c.y * c.y + c.z * c.z + c.w * c.w;
#pragma unroll
    for (int off = 32; off > 0; off >>= 1) {
        s += __shfl_xor(s, off, 64);
        sq += __shfl_xor(sq, off, 64);
    }
    float mu = s * (1.f / 512.f);
    float var = sq * (1.f / 512.f) - mu * mu;
    float rstd = rsqrtf(var + 1e-5f);
    float4 g0 = *(const float4*)(g + lane * 8);
    float4 g1 = *(const float4*)(g + lane * 8 + 4);
    float4 b0 = *(const float4*)(bta + lane * 8);
    float4 b1 = *(const float4*)(bta + lane * 8 + 4);
    float y0 = (a.x - mu) * rstd * g0.x + b0.x;
    float y1 = (a.y - mu) * rstd * g0.y + b0.y;
    float y2 = (a.z - mu) * rstd * g0.z + b0.z;
    float y3 = (a.w - mu) * rstd * g0.w + b0.w;
    float y4 = (c.x - mu) * rstd * g1.x + b1.x;
    float y5 = (c.y - mu) * rstd * g1.y + b1.y;
    float y6 = (c.z - mu) * rstd * g1.z + b1.z;
    float y7 = (c.w - mu) * rstd * g1.w + b1.w;
    if (out_f32) {
        float* o = OutF + row * 512 + lane * 8;
        *(float4*)(o) = make_float4(y0, y1, y2, y3);
        *(float4*)(o + 4) = make_float4(y4, y5, y6, y7);
    } else {
        u32 w0 = (u32)f2bf(y0) | ((u32)f2bf(y1) << 16);
        u32 w1 = (u32)f2bf(y2) | ((u32)f2bf(y3) << 16);
        u32 w2 = (u32)f2bf(y4) | ((u32)f2bf(y5) << 16);
        u32 w3 = (u32)f2bf(y6) | ((u32)f2bf(y7) << 16);
        uint4 o = {w0, w1, w2, w3};
        *(uint4*)(OutB + row * 512 + lane * 8) = o;
    }
}

// ---------------------------------------------------------------------------
extern "C" void kernel_launch(void* const* d_in, const int* in_sizes, int n_in,
                              void* d_out, int out_size, void* d_ws, size_t ws_size,
                              hipStream_t stream) {
    const float* q  = (const float*)d_in[0];
    const float* k  = (const float*)d_in[1];
    const float* v  = (const float*)d_in[2];
    const float* Wq = (const float*)d_in[3];
    const float* Wk = (const float*)d_in[4];
    const float* Wv = (const float*)d_in[5];
    const float* Wm = (const float*)d_in[6];
    const float* W1 = (const float*)d_in[7];
    const float* W2 = (const float*)d_in[8];
    const float* g1 = (const float*)d_in[9];
    const float* b1 = (const float*)d_in[10];
    const float* g2 = (const float*)d_in[11];
    const float* b2 = (const float*)d_in[12];

    char* ws = (char*)d_ws;
    // workspace layout (bytes); high-water ~124MB
    u16* WTq = (u16*)(ws + 0);            // 512KB each; WTq..WTm contiguous
    u16* W1T = (u16*)(ws + 2097152);      // [2048,512] 2MB; W1T|W2T contiguous
    u16* qc  = (u16*)(ws + 6291456);      // bf16 casts, CONTIGUOUS 16.8MB each
    u16* Qb  = (u16*)(ws + 56623104);     // projections, CONTIGUOUS 16.8MB each
    u16* Kb  = (u16*)(ws + 73400320);
    u16* Vb  = (u16*)(ws + 90177536);
    float* KVb = (float*)(ws + 106954752); // 512KB
    float* KSb = (float*)(ws + 107479040); // 8KB
    u16* Msg = (u16*)(ws + 107487232);    // 16.8MB -> high-water 124264448
    float* Part = (float*)(ws + 23068672); // 16.8MB partial KV (kc/vc dead)
    float* KsPart = (float*)(ws + 6291456);// 256KB (qc dead after projections)
    float* xpre = (float*)(ws + 23068672); // 33.5MB (Part dead after reduce)
    u16* x1  = qc;                         // reuses qc (KsPart dead by LN1)
    u16* Hid = (u16*)(ws + 56623104);     // 67MB, reuses Qb..Msg (dead at FFN)

    // fused casts + transposes (one dispatch)
    prep_k<<<dim3(36864), 256, 0, stream>>>(q, k, v, Wq, Wk, Wv, Wm, W1, W2,
                                            qc, WTq, W1T);

    // batched q/k/v projections: one dispatch, N=1536 (BK=32; 1536 blocks)
    gemm_bt<<<dim3(12, 128), 256, 0, stream>>>(qc, WTq, Qb, nullptr, 16384, 1536, 512, EPI_PROJ3);

    // linear attention: MFMA two-stage KV, then msg
    kv_part<<<dim3(32, 32), 256, 0, stream>>>(Kb, Vb, Part, KsPart);
    kv_reduce<<<dim3(520), 256, 0, stream>>>(Part, KsPart, KVb, KSb);
    msg_k<<<dim3(32, 64), 256, 0, stream>>>(Qb, KVb, KSb, Msg);

    // merge + residual(q fp32) + LN1
    gemm_bt64<<<dim3(4, 128), 256, 0, stream>>>(Msg, (u16*)(ws + 1572864), xpre, q, 16384, 512, 512, EPI_ADDRES_F32);
    ln_k<<<dim3(4096), 256, 0, stream>>>(xpre, g1, b1, x1, nullptr, 0);

    // FFN1 (BK=64 now: barriers/residency 8/2 < BK32's 16/2.7)
    gemm_bt64<<<dim3(16, 128), 256, 0, stream>>>(x1, W1T, Hid, nullptr, 16384, 2048, 512, EPI_RELU);
    // FFN2 (BK=64)
    gemm_bt64<<<dim3(4, 128), 256, 0, stream>>>(Hid, (u16*)(ws + 4194304), xpre, q, 16384, 512, 2048, EPI_ADDRES_F32);
    ln_k<<<dim3(4096), 256, 0, stream>>>(xpre, g2, b2, nullptr, (float*)d_out, 1);
}

// Round 11
// 421.588 us; speedup vs baseline: 1.4217x; 1.0512x over previous
//
#include <hip/hip_runtime.h>

typedef unsigned short u16;
typedef unsigned int u32;

typedef __bf16 bf16x8 __attribute__((ext_vector_type(8)));
typedef float f32x4 __attribute__((ext_vector_type(4)));

#define EPI_BF16 0
#define EPI_ELU1 1
#define EPI_RELU 2
#define EPI_ADDRES_F32 3

__device__ __forceinline__ float bf2f(u16 x) {
    u32 u = ((u32)x) << 16;
    return __uint_as_float(u);
}
__device__ __forceinline__ u16 f2bf(float f) {
    u32 u = __float_as_uint(f);
    u32 r = (u + 0x7FFFu + ((u >> 16) & 1u)) >> 16;
    return (u16)r;
}
__device__ __forceinline__ u32 pack2(float a, float b) {
    return (u32)f2bf(a) | ((u32)f2bf(b) << 16);
}

// async global->LDS, 16B per lane; LDS dest = wave-uniform base + lane*16
__device__ __forceinline__ void gload_lds16(const u16* g, u16* l) {
    __builtin_amdgcn_global_load_lds(
        (const __attribute__((address_space(1))) u32*)g,
        (__attribute__((address_space(3))) u32*)l, 16, 0, 0);
}

// ---------------------------------------------------------------------------
// prep: weight transposes + cast ONLY (q/k/v cast is now fused into proj3's
// A-staging — its 150MB round-trip was pure waste). grid 12288.
// blocks [0,4096): Wq..Wm 512x512; [4096,12288): W1/W2.
// ---------------------------------------------------------------------------
__global__ __launch_bounds__(256) void prep_k(
    const float* __restrict__ Wq, const float* __restrict__ Wk,
    const float* __restrict__ Wv, const float* __restrict__ Wm,
    const float* __restrict__ W1, const float* __restrict__ W2,
    u16* __restrict__ wt4_out, u16* __restrict__ wt2_out)
{
    int bid = blockIdx.x;
    if (bid < 4096) {
        int idx = bid * 256 + threadIdx.x;               // 4*262144
        int w = idx >> 18, local = idx & 262143;
        const float* in = (w == 0) ? Wq : (w == 1) ? Wk : (w == 2) ? Wv : Wm;
        int c = local >> 9, r = local & 511;
        wt4_out[idx] = f2bf(in[r * 512 + c]);
    } else {
        int idx = (bid - 4096) * 256 + threadIdx.x;      // 2*1048576
        if (idx < 1048576) {
            int c = idx / 512, r = idx % 512;
            wt2_out[idx] = f2bf(W1[(long)r * 2048 + c]);
        } else {
            int local = idx - 1048576;
            int c = local / 2048, r = local % 2048;
            wt2_out[idx] = f2bf(W2[(long)r * 512 + c]);
        }
    }
}

// ---------------------------------------------------------------------------
// Batched q/k/v projection GEMM with FUSED fp32->bf16 cast of A.
// C[16384,1536] = cast(q|k|v)[16384,512] @ WT[1536,512]^T, elu+1 for q,k.
// BK=32, 128x128 tile, 4 waves, r3 schedule. A is reg-staged (float4 loads ->
// f2bf -> ds_write_b128 to the SAME linear slot the DMA path used; T14
// issue-early/write-late split); B stays global_load_lds. Same f2bf rounding
// as the old prep cast -> bit-identical A operands. XCD-chunked swizzle.
// ---------------------------------------------------------------------------
__global__ __launch_bounds__(256) void gemm_proj3(
    const float* __restrict__ Aq, const float* __restrict__ Ak,
    const float* __restrict__ Av, const u16* __restrict__ Bt,
    u16* __restrict__ C)
{
    __shared__ __align__(16) u16 As[2][4096];
    __shared__ __align__(16) u16 Bs[2][4096];

    int t = threadIdx.x;
    int gx = gridDim.x;                      // 12
    int nwg = gx * gridDim.y;                // 1536 (%8==0)
    int bid = blockIdx.y * gx + blockIdx.x;
    {
        int cpx = nwg >> 3;
        bid = (bid & 7) * cpx + (bid >> 3);
    }
    int m0 = (bid / gx) * 128, n0 = (bid % gx) * 128;
    int third = n0 >> 9;                     // 0:q 1:k 2:v
    const float* Af = (third == 0) ? Aq : (third == 1) ? Ak : Av;

    int wave = t >> 6, lane = t & 63;
    int wm = (wave >> 1) * 64, wn = (wave & 1) * 64;
    int lrow = lane & 15, lk8 = (lane >> 4) * 8;

    f32x4 acc[4][4] = {};

    int srow = wave * 16 + (lane >> 2);
    int scol = (lane & 3) * 8;
    const float* pAf = Af + (long)(m0 + srow) * 512 + scol;
    const u16* pB0 = Bt + (long)(n0 + srow) * 512 + scol;
    const long s64 = (long)64 * 512;
    u16* myA0 = (u16*)As[0];                 // per-buffer write slots
    u16* myA1 = (u16*)As[1];
    int wslot = wave * 512 + lane * 8;       // u16 index (matches DMA layout)

    int nt = 16;                             // K=512 / 32
    int cur = 0;

    // prologue: tile 0
    {
        float4 a0 = *(const float4*)(pAf);
        float4 a1 = *(const float4*)(pAf + 4);
        float4 a2 = *(const float4*)(pAf + s64);
        float4 a3 = *(const float4*)(pAf + s64 + 4);
        gload_lds16(pB0, Bs[0] + wave * 512);
        gload_lds16(pB0 + s64, Bs[0] + wave * 512 + 2048);
        uint4 w0 = {pack2(a0.x, a0.y), pack2(a0.z, a0.w),
                    pack2(a1.x, a1.y), pack2(a1.z, a1.w)};
        uint4 w1 = {pack2(a2.x, a2.y), pack2(a2.z, a2.w),
                    pack2(a3.x, a3.y), pack2(a3.z, a3.w)};
        *(uint4*)(myA0 + wslot) = w0;
        *(uint4*)(myA0 + wslot + 2048) = w1;
    }
    __builtin_amdgcn_s_waitcnt(0);
    __syncthreads();

    for (int kt = 0; kt < nt; ++kt) {
        float4 a0, a1, a2, a3;
        if (kt + 1 < nt) {
            int k0 = (kt + 1) << 5;
            u16* b = Bs[cur ^ 1] + wave * 512;
            gload_lds16(pB0 + k0, b);
            gload_lds16(pB0 + s64 + k0, b + 2048);
            a0 = *(const float4*)(pAf + k0);
            a1 = *(const float4*)(pAf + k0 + 4);
            a2 = *(const float4*)(pAf + s64 + k0);
            a3 = *(const float4*)(pAf + s64 + k0 + 4);
        }

        const u16* As_c = As[cur];
        const u16* Bs_c = Bs[cur];
        bf16x8 af[4], bfr[4];
#pragma unroll
        for (int mi = 0; mi < 4; mi++)
            af[mi] = *(const bf16x8*)(As_c + (wm + mi * 16 + lrow) * 32 + lk8);
#pragma unroll
        for (int ni = 0; ni < 4; ni++)
            bfr[ni] = *(const bf16x8*)(Bs_c + (wn + ni * 16 + lrow) * 32 + lk8);
#pragma unroll
        for (int mi = 0; mi < 4; mi++)
#pragma unroll
            for (int ni = 0; ni < 4; ni++)
                acc[mi][ni] = __builtin_amdgcn_mfma_f32_16x16x32_bf16(
                    af[mi], bfr[ni], acc[mi][ni], 0, 0, 0);

        if (kt + 1 < nt) {
            __builtin_amdgcn_s_waitcnt(0);   // A regs + B DMA landed
            u16* dst = (cur == 0) ? myA1 : myA0;
            uint4 w0 = {pack2(a0.x, a0.y), pack2(a0.z, a0.w),
                        pack2(a1.x, a1.y), pack2(a1.z, a1.w)};
            uint4 w1 = {pack2(a2.x, a2.y), pack2(a2.z, a2.w),
                        pack2(a3.x, a3.y), pack2(a3.z, a3.w)};
            *(uint4*)(dst + wslot) = w0;
            *(uint4*)(dst + wslot + 2048) = w1;
            __syncthreads();                 // drains lgkm (ds_writes) too
            cur ^= 1;
        }
    }

    // Epilogue: D[row=(lane>>4)*4+r][col=lane&15]; elu+1 for thirds 0,1
    int rq = (lane >> 4) * 4;
    int colb = n0 + wn + (lane & 15);
    u16* Cb = C + (long)third * 8388608;
#pragma unroll
    for (int mi = 0; mi < 4; mi++) {
#pragma unroll
        for (int ni = 0; ni < 4; ni++) {
#pragma unroll
            for (int r = 0; r < 4; r++) {
                int row = m0 + wm + mi * 16 + rq + r;
                int col = colb + ni * 16 - (third << 9);
                float v0 = acc[mi][ni][r];
                float v = (third < 2)
                              ? (v0 > 0.f ? v0 + 1.f : __expf(v0))
                              : v0;
                Cb[(long)row * 512 + col] = f2bf(v);
            }
        }
    }
}

// ---------------------------------------------------------------------------
// GEMM BK=64 (r9/r10 verified): 32 MFMAs per barrier. Used for merge, FFN1,
// FFN2. r10 A/B: BK64 vs BK32 at 2048 blocks ~neutral (74.7 vs 76.2) -> keep.
// ---------------------------------------------------------------------------
__global__ __launch_bounds__(256) void gemm_bt64(
    const u16* __restrict__ A, const u16* __restrict__ Bt,
    void* __restrict__ C, const float* __restrict__ Res,
    int M, int N, int K, int epi)
{
    __shared__ __align__(16) u16 As[2][8192];
    __shared__ __align__(16) u16 Bs[2][8192];

    int t = threadIdx.x;
    int gx = gridDim.x;
    int nwg = gx * gridDim.y;
    int bid = blockIdx.y * gx + blockIdx.x;
    if ((nwg & 7) == 0) {
        int cpx = nwg >> 3;
        bid = (bid & 7) * cpx + (bid >> 3);
    }
    int m0 = (bid / gx) * 128, n0 = (bid % gx) * 128;

    int wave = t >> 6, lane = t & 63;
    int wm = (wave >> 1) * 64, wn = (wave & 1) * 64;
    int lrow = lane & 15, lk8 = (lane >> 4) * 8;

    f32x4 acc[4][4] = {};

    int srow = wave * 16 + (lane >> 2);
    int scol = (lane & 3) * 8;
    const u16* pA0 = A + (long)(m0 + srow) * K + scol;
    const u16* pB0 = Bt + (long)(n0 + srow) * K + scol;
    const long s64 = (long)64 * K;

    int nt = K >> 6;
    int cur = 0;

    {
        u16* a = As[0] + wave * 512;
        u16* b = Bs[0] + wave * 512;
#pragma unroll
        for (int kk = 0; kk < 2; kk++) {
            gload_lds16(pA0 + kk * 32, a + kk * 4096);
            gload_lds16(pA0 + s64 + kk * 32, a + kk * 4096 + 2048);
            gload_lds16(pB0 + kk * 32, b + kk * 4096);
            gload_lds16(pB0 + s64 + kk * 32, b + kk * 4096 + 2048);
        }
    }
    __builtin_amdgcn_s_waitcnt(0);
    __syncthreads();

    for (int kt = 0; kt < nt; ++kt) {
        if (kt + 1 < nt) {
            int k0 = (kt + 1) << 6;
            u16* a = As[cur ^ 1] + wave * 512;
            u16* b = Bs[cur ^ 1] + wave * 512;
#pragma unroll
            for (int kk = 0; kk < 2; kk++) {
                gload_lds16(pA0 + k0 + kk * 32, a + kk * 4096);
                gload_lds16(pA0 + s64 + k0 + kk * 32, a + kk * 4096 + 2048);
                gload_lds16(pB0 + k0 + kk * 32, b + kk * 4096);
                gload_lds16(pB0 + s64 + k0 + kk * 32, b + kk * 4096 + 2048);
            }
        }

#pragma unroll
        for (int kk = 0; kk < 2; kk++) {
            const u16* As_c = As[cur] + kk * 4096;
            const u16* Bs_c = Bs[cur] + kk * 4096;
            bf16x8 af[4], bfr[4];
#pragma unroll
            for (int mi = 0; mi < 4; mi++)
                af[mi] = *(const bf16x8*)(As_c + (wm + mi * 16 + lrow) * 32 + lk8);
#pragma unroll
            for (int ni = 0; ni < 4; ni++)
                bfr[ni] = *(const bf16x8*)(Bs_c + (wn + ni * 16 + lrow) * 32 + lk8);
#pragma unroll
            for (int mi = 0; mi < 4; mi++)
#pragma unroll
                for (int ni = 0; ni < 4; ni++)
                    acc[mi][ni] = __builtin_amdgcn_mfma_f32_16x16x32_bf16(
                        af[mi], bfr[ni], acc[mi][ni], 0, 0, 0);
        }

        if (kt + 1 < nt) {
            __builtin_amdgcn_s_waitcnt(0);
            __syncthreads();
            cur ^= 1;
        }
    }

    int rq = (lane >> 4) * 4;
    int colb = n0 + wn + (lane & 15);
#pragma unroll
    for (int mi = 0; mi < 4; mi++) {
#pragma unroll
        for (int ni = 0; ni < 4; ni++) {
#pragma unroll
            for (int r = 0; r < 4; r++) {
                int row = m0 + wm + mi * 16 + rq + r;
                int col = colb + ni * 16;
                long idx = (long)row * N + col;
                float v0 = acc[mi][ni][r];
                if (epi == EPI_ELU1) {
                    float v = v0 > 0.f ? v0 + 1.f : __expf(v0);
                    ((u16*)C)[idx] = f2bf(v);
                } else if (epi == EPI_RELU) {
                    ((u16*)C)[idx] = f2bf(v0 > 0.f ? v0 : 0.f);
                } else if (epi == EPI_ADDRES_F32) {
                    ((float*)C)[idx] = v0 + Res[idx];
                } else {
                    ((u16*)C)[idx] = f2bf(v0);
                }
            }
        }
    }
}

// ---------------------------------------------------------------------------
// KV stage 1, MFMA (r10-verified). grid (32,32).
// ---------------------------------------------------------------------------
__global__ __launch_bounds__(256) void kv_part(
    const u16* __restrict__ Kf, const u16* __restrict__ Vf,
    float* __restrict__ Part, float* __restrict__ KsPart)
{
    __shared__ __align__(16) u16 sKt[64 * 72];   // [d][s]
    __shared__ __align__(16) u16 sVt[64 * 72];   // [v][s]
    int bh = blockIdx.x;
    int b = bh >> 3, h = bh & 7;
    int t = threadIdx.x;
    int wave = t >> 6, lane = t & 63;
    int dblk = (wave >> 1) * 32, vblk = (wave & 1) * 32;
    int lrow = lane & 15, lk8 = (lane >> 4) * 8;

    f32x4 acc[2][2] = {};
    float ks = 0.f;

    int srow = t >> 2, c16 = (t & 3) * 16;

    for (int st = 0; st < 2; ++st) {
        int s0 = blockIdx.y * 128 + st * 64;
        {
            long g = ((long)b * 4096 + s0 + srow) * 512 + h * 64 + c16;
            uint4 k0 = *(const uint4*)(Kf + g);
            uint4 k1 = *(const uint4*)(Kf + g + 8);
            uint4 v0 = *(const uint4*)(Vf + g);
            uint4 v1 = *(const uint4*)(Vf + g + 8);
            u32 kw[8] = {k0.x, k0.y, k0.z, k0.w, k1.x, k1.y, k1.z, k1.w};
            u32 vw[8] = {v0.x, v0.y, v0.z, v0.w, v1.x, v1.y, v1.z, v1.w};
            if (st) __syncthreads();
#pragma unroll
            for (int j = 0; j < 16; j++) {
                u16 kv_ = (u16)(kw[j >> 1] >> ((j & 1) * 16));
                u16 vv_ = (u16)(vw[j >> 1] >> ((j & 1) * 16));
                sKt[(c16 + j) * 72 + srow] = kv_;
                sVt[(c16 + j) * 72 + srow] = vv_;
            }
        }
        __syncthreads();

#pragma unroll
        for (int ksb = 0; ksb < 2; ++ksb) {
            int ko = ksb * 32 + lk8;
            bf16x8 a0 = *(const bf16x8*)(sKt + (dblk + lrow) * 72 + ko);
            bf16x8 a1 = *(const bf16x8*)(sKt + (dblk + 16 + lrow) * 72 + ko);
            bf16x8 b0 = *(const bf16x8*)(sVt + (vblk + lrow) * 72 + ko);
            bf16x8 b1 = *(const bf16x8*)(sVt + (vblk + 16 + lrow) * 72 + ko);
            acc[0][0] = __builtin_amdgcn_mfma_f32_16x16x32_bf16(a0, b0, acc[0][0], 0, 0, 0);
            acc[0][1] = __builtin_amdgcn_mfma_f32_16x16x32_bf16(a0, b1, acc[0][1], 0, 0, 0);
            acc[1][0] = __builtin_amdgcn_mfma_f32_16x16x32_bf16(a1, b0, acc[1][0], 0, 0, 0);
            acc[1][1] = __builtin_amdgcn_mfma_f32_16x16x32_bf16(a1, b1, acc[1][1], 0, 0, 0);
        }

        if (t < 64) {
            const u32* rowp = (const u32*)(sKt + t * 72);
#pragma unroll
            for (int c = 0; c < 32; c++) {
                u32 w = rowp[c];
                ks += bf2f((u16)w) + bf2f((u16)(w >> 16));
            }
        }
    }

    int rq = (lane >> 4) * 4;
    float* pp = Part + ((long)bh * 32 + blockIdx.y) * 4096;
#pragma unroll
    for (int ti = 0; ti < 2; ti++)
#pragma unroll
        for (int tj = 0; tj < 2; tj++)
#pragma unroll
            for (int r = 0; r < 4; r++) {
                int d = dblk + ti * 16 + rq + r;
                int vcol = vblk + tj * 16 + (lane & 15);
                pp[d * 64 + vcol] = acc[ti][tj][r];
            }
    if (t < 64) KsPart[((bh * 32) + blockIdx.y) * 64 + t] = ks;
}

// ---------------------------------------------------------------------------
// KV stage 2: reduce splits -> KV; emit bf16 SPLIT (hi,lo) TRANSPOSED copies
// [v][d] for msg's MFMA B-operand (hi+lo recovers fp32-level precision).
// Ksum in tail blocks.
// ---------------------------------------------------------------------------
__global__ __launch_bounds__(256) void kv_reduce(
    const float* __restrict__ Part, const float* __restrict__ KsPart,
    u16* __restrict__ KVthi, u16* __restrict__ KVtlo,
    float* __restrict__ Ksum)
{
    int i = blockIdx.x * 256 + threadIdx.x;
    if (i < 131072) {
        int bh = i >> 12, dv = i & 4095;
        int d = dv >> 6, v = dv & 63;
        const float* p = Part + (long)bh * 32 * 4096 + dv;
        float s = 0.f;
#pragma unroll 8
        for (int sp = 0; sp < 32; sp++) s += p[(long)sp * 4096];
        u16 hi = f2bf(s);
        u16 lo = f2bf(s - bf2f(hi));
        long o = (long)bh * 4096 + v * 64 + d;   // transposed [v][d]
        KVthi[o] = hi;
        KVtlo[o] = lo;
    } else if (i < 133120) {
        int j = i - 131072;
        int bh = j >> 6, d = j & 63;
        const float* p = KsPart + bh * 32 * 64 + d;
        float s = 0.f;
#pragma unroll 8
        for (int sp = 0; sp < 32; sp++) s += p[sp * 64];
        Ksum[j] = s;
    }
}

// ---------------------------------------------------------------------------
// msg via MFMA: C[l,v] = sum_d Q[l,d] * (KVhi+KVlo)[v,d], then * 1/(Q.Ks+eps).
// Block (bh, 64 l-rows). Q, KVthi, KVtlo staged reg->LDS with pad-72 rows
// (kv_part-proven conflict-free pitch). 4 waves, each a 16-row slab: 16 MFMAs
// (4 v-tiles x 2 k-halves x hi/lo into the SAME acc). Z on wave-0 lanes
// overlaps other waves' MFMAs. Replaces the VALU GEMM (~256 LDS reads +
// ~1024 FMA per thread).
// ---------------------------------------------------------------------------
__global__ __launch_bounds__(256) void msg_k(
    const u16* __restrict__ Q, const u16* __restrict__ KVthi,
    const u16* __restrict__ KVtlo, const float* __restrict__ Ksum,
    u16* __restrict__ Msg)
{
    __shared__ __align__(16) u16 sQ[64 * 72];    // [l][d]
    __shared__ __align__(16) u16 sHi[64 * 72];   // [v][d]
    __shared__ __align__(16) u16 sLo[64 * 72];
    __shared__ float sKs[64];
    __shared__ float sZ[64];

    int bh = blockIdx.x;
    int b = bh >> 3, h = bh & 7;
    int l0 = blockIdx.y * 64;
    int t = threadIdx.x, wave = t >> 6, lane = t & 63;

    // stage: 512 16B-chunks per array; thread t covers chunks {t, t+256}
#pragma unroll
    for (int p = 0; p < 2; ++p) {
        int c = t + p * 256;
        int row = c >> 3, cc = c & 7;
        int dsto = row * 72 + cc * 8;
        uint4 qv = *(const uint4*)(Q + ((long)b * 4096 + l0 + row) * 512 +
                                   h * 64 + cc * 8);
        uint4 hv = *(const uint4*)(KVthi + (long)bh * 4096 + c * 8);
        uint4 lv = *(const uint4*)(KVtlo + (long)bh * 4096 + c * 8);
        *(uint4*)(sQ + dsto) = qv;
        *(uint4*)(sHi + dsto) = hv;
        *(uint4*)(sLo + dsto) = lv;
    }
    if (t < 64) sKs[t] = Ksum[bh * 64 + t];
    __syncthreads();

    // Z on wave 0 (overlaps other waves' MFMA work)
    if (t < 64) {
        float zp = 0.f;
#pragma unroll
        for (int d = 0; d < 64; d++) zp += bf2f(sQ[t * 72 + d]) * sKs[d];
        sZ[t] = 1.f / (zp + 1e-6f);
    }

    int lrow = lane & 15, lk8 = (lane >> 4) * 8;
    bf16x8 af[2];
#pragma unroll
    for (int ksb = 0; ksb < 2; ksb++)
        af[ksb] = *(const bf16x8*)(sQ + (wave * 16 + lrow) * 72 + ksb * 32 + lk8);

    f32x4 acc[4] = {};
#pragma unroll
    for (int vt = 0; vt < 4; vt++) {
#pragma unroll
        for (int ksb = 0; ksb < 2; ksb++) {
            int bo = (vt * 16 + lrow) * 72 + ksb * 32 + lk8;
            bf16x8 bh_ = *(const bf16x8*)(sHi + bo);
            bf16x8 bl_ = *(const bf16x8*)(sLo + bo);
            acc[vt] = __builtin_amdgcn_mfma_f32_16x16x32_bf16(af[ksb], bh_, acc[vt], 0, 0, 0);
            acc[vt] = __builtin_amdgcn_mfma_f32_16x16x32_bf16(af[ksb], bl_, acc[vt], 0, 0, 0);
        }
    }
    __syncthreads();   // sZ ready

    int rq = (lane >> 4) * 4;
#pragma unroll
    for (int vt = 0; vt < 4; vt++) {
#pragma unroll
        for (int r = 0; r < 4; r++) {
            int ll = wave * 16 + rq + r;
            int v = vt * 16 + (lane & 15);
            float out = acc[vt][r] * sZ[ll];
            Msg[((long)b * 4096 + l0 + ll) * 512 + h * 64 + v] = f2bf(out);
        }
    }
}

// ---------------------------------------------------------------------------
// LayerNorm, wave-per-row (r10-verified). 4 rows/block, grid 4096.
// ---------------------------------------------------------------------------
__global__ __launch_bounds__(256) void ln_k(
    const float* __restrict__ X, const float* __restrict__ g,
    const float* __restrict__ bta, u16* __restrict__ OutB,
    float* __restrict__ OutF, int out_f32)
{
    int wave = threadIdx.x >> 6, lane = threadIdx.x & 63;
    long row = (long)blockIdx.x * 4 + wave;
    const float* x = X + row * 512 + lane * 8;
    float4 a = *(const float4*)(x);
    float4 c = *(const float4*)(x + 4);
    float s = (a.x + a.y) + (a.z + a.w) + (c.x + c.y) + (c.z + c.w);
    float sq = a.x * a.x + a.y * a.y + a.z * a.z + a.w * a.w +
               c.x * c.x + c.y * c.y + c.z * c.z + c.w * c.w;
#pragma unroll
    for (int off = 32; off > 0; off >>= 1) {
        s += __shfl_xor(s, off, 64);
        sq += __shfl_xor(sq, off, 64);
    }
    float mu = s * (1.f / 512.f);
    float var = sq * (1.f / 512.f) - mu * mu;
    float rstd = rsqrtf(var + 1e-5f);
    float4 g0 = *(const float4*)(g + lane * 8);
    float4 g1 = *(const float4*)(g + lane * 8 + 4);
    float4 b0 = *(const float4*)(bta + lane * 8);
    float4 b1 = *(const float4*)(bta + lane * 8 + 4);
    float y0 = (a.x - mu) * rstd * g0.x + b0.x;
    float y1 = (a.y - mu) * rstd * g0.y + b0.y;
    float y2 = (a.z - mu) * rstd * g0.z + b0.z;
    float y3 = (a.w - mu) * rstd * g0.w + b0.w;
    float y4 = (c.x - mu) * rstd * g1.x + b1.x;
    float y5 = (c.y - mu) * rstd * g1.y + b1.y;
    float y6 = (c.z - mu) * rstd * g1.z + b1.z;
    float y7 = (c.w - mu) * rstd * g1.w + b1.w;
    if (out_f32) {
        float* o = OutF + row * 512 + lane * 8;
        *(float4*)(o) = make_float4(y0, y1, y2, y3);
        *(float4*)(o + 4) = make_float4(y4, y5, y6, y7);
    } else {
        u32 w0 = (u32)f2bf(y0) | ((u32)f2bf(y1) << 16);
        u32 w1 = (u32)f2bf(y2) | ((u32)f2bf(y3) << 16);
        u32 w2 = (u32)f2bf(y4) | ((u32)f2bf(y5) << 16);
        u32 w3 = (u32)f2bf(y6) | ((u32)f2bf(y7) << 16);
        uint4 o = {w0, w1, w2, w3};
        *(uint4*)(OutB + row * 512 + lane * 8) = o;
    }
}

// ---------------------------------------------------------------------------
extern "C" void kernel_launch(void* const* d_in, const int* in_sizes, int n_in,
                              void* d_out, int out_size, void* d_ws, size_t ws_size,
                              hipStream_t stream) {
    const float* q  = (const float*)d_in[0];
    const float* k  = (const float*)d_in[1];
    const float* v  = (const float*)d_in[2];
    const float* Wq = (const float*)d_in[3];
    const float* Wk = (const float*)d_in[4];
    const float* Wv = (const float*)d_in[5];
    const float* Wm = (const float*)d_in[6];
    const float* W1 = (const float*)d_in[7];
    const float* W2 = (const float*)d_in[8];
    const float* g1 = (const float*)d_in[9];
    const float* b1 = (const float*)d_in[10];
    const float* g2 = (const float*)d_in[11];
    const float* b2 = (const float*)d_in[12];

    char* ws = (char*)d_ws;
    // workspace layout (bytes); high-water ~124MB
    u16* WTq = (u16*)(ws + 0);            // 512KB each; WTq..WTm contiguous
    u16* W1T = (u16*)(ws + 2097152);      // 2MB W1T | 2MB W2T contiguous
    u16* Qb  = (u16*)(ws + 56623104);     // projections, CONTIGUOUS 16.8MB each
    u16* Kb  = (u16*)(ws + 73400320);
    u16* Vb  = (u16*)(ws + 90177536);
    u16* KVthi = (u16*)(ws + 106954752);  // 256KB [bh][v*64+d] bf16
    u16* KVtlo = (u16*)(ws + 107216896);  // 256KB
    float* KSb = (float*)(ws + 107479040); // 8KB
    u16* Msg = (u16*)(ws + 107487232);    // 16.8MB -> high-water 124264448
    float* Part = (float*)(ws + 23068672); // 16.8MB partial KV
    float* KsPart = (float*)(ws + 6291456);// 256KB
    float* xpre = (float*)(ws + 23068672); // 33.5MB (Part dead after reduce)
    u16* x1  = (u16*)(ws + 6291456);       // 16.8MB (KsPart dead by LN1)
    u16* Hid = (u16*)(ws + 56623104);     // 67MB, reuses Qb..Msg (dead at FFN)

    // weight transposes only (q/k/v cast fused into proj GEMM)
    prep_k<<<dim3(12288), 256, 0, stream>>>(Wq, Wk, Wv, Wm, W1, W2, WTq, W1T);

    // batched q/k/v projections with fused fp32->bf16 A cast
    gemm_proj3<<<dim3(12, 128), 256, 0, stream>>>(q, k, v, WTq, Qb);

    // linear attention: MFMA two-stage KV (split-bf16 transposed out), MFMA msg
    kv_part<<<dim3(32, 32), 256, 0, stream>>>(Kb, Vb, Part, KsPart);
    kv_reduce<<<dim3(520), 256, 0, stream>>>(Part, KsPart, KVthi, KVtlo, KSb);
    msg_k<<<dim3(32, 64), 256, 0, stream>>>(Qb, KVthi, KVtlo, KSb, Msg);

    // merge + residual(q fp32) + LN1
    gemm_bt64<<<dim3(4, 128), 256, 0, stream>>>(Msg, (u16*)(ws + 1572864), xpre, q, 16384, 512, 512, EPI_ADDRES_F32);
    ln_k<<<dim3(4096), 256, 0, stream>>>(xpre, g1, b1, x1, nullptr, 0);

    // FFN
    gemm_bt64<<<dim3(16, 128), 256, 0, stream>>>(x1, W1T, Hid, nullptr, 16384, 2048, 512, EPI_RELU);
    gemm_bt64<<<dim3(4, 128), 256, 0, stream>>>(Hid, (u16*)(ws + 4194304), xpre, q, 16384, 512, 2048, EPI_ADDRES_F32);
    ln_k<<<dim3(4096), 256, 0, stream>>>(xpre, g2, b2, nullptr, (float*)d_out, 1);
}